// Round 2
// baseline (22665.157 us; speedup 1.0000x reference)
//
#include <hip/hip_runtime.h>
#include <math.h>

#define EMB 512
#define HEADS 8
#define NLAYERS 4
#define NB 32
#define SEQ 200
#define TOKN 50
#define DH 64
#define FFND 2048
#define NCLS 204

// Block reduction: sum or max across the whole block. Identity must be fed by
// threads with no data (0 for sum, -INF for max). Call from uniform control flow.
__device__ __forceinline__ float block_reduce(float v, float* red, int nwaves, bool domax){
  int tid = threadIdx.x;
  #pragma unroll
  for (int o = 32; o > 0; o >>= 1){
    float t = __shfl_down(v, o, 64);
    v = domax ? fmaxf(v, t) : (v + t);
  }
  __syncthreads();                 // protect red from previous use
  if ((tid & 63) == 0) red[tid >> 6] = v;
  __syncthreads();
  float r = red[0];
  for (int i = 1; i < nwaves; i++) r = domax ? fmaxf(r, red[i]) : (r + red[i]);
  return r;
}

// ---------------------------------------------------------------------------
// TextCNN fused: gather-embed + (conv1/2/3 as 600-ch GEMM) + relu/maxpool +
// 300->512 FC + ln_free. One block per sequence row (6400 rows).
// ---------------------------------------------------------------------------
__global__ __launch_bounds__(640) void textcnn_kernel(
    const int* __restrict__ src, const float* __restrict__ emb,
    const float* __restrict__ cw1, const float* __restrict__ cb1,
    const float* __restrict__ cw2, const float* __restrict__ cb2,
    const float* __restrict__ cw3, const float* __restrict__ cb3,
    const float* __restrict__ tfw, const float* __restrict__ tfb,
    float* __restrict__ base)
{
  __shared__ int toks[TOKN];
  __shared__ float E[TOKN][16];
  __shared__ float stage[2][100][50];
  __shared__ float pooled[300];
  __shared__ float red[12];

  const int tid = threadIdx.x;
  const int r = blockIdx.x;
  if (tid < TOKN) toks[tid] = src[r * TOKN + tid];
  __syncthreads();

  const int c = tid;
  float acc[TOKN];
  #pragma unroll
  for (int p = 0; p < TOKN; p++) acc[p] = 0.f;

  const float* wrow = nullptr;
  if (c < 100)      { wrow = cw1 + (size_t)c * 1024; }
  else if (c < 300) { int o = (c - 100) % 100, sub = (c - 100) / 100; wrow = cw2 + (size_t)(o * 2 + sub) * 1024; }
  else if (c < 600) { int o = (c - 300) % 100, sub = (c - 300) / 100; wrow = cw3 + (size_t)(o * 3 + sub) * 1024; }

  for (int k0 = 0; k0 < 1024; k0 += 16){
    if (tid < 100){
      int p = tid >> 1, half = tid & 1;
      const float4* ep = (const float4*)(emb + (size_t)toks[p] * 1024 + k0 + half * 8);
      float4 e0 = ep[0], e1 = ep[1];
      float4* er = (float4*)&E[p][half * 8];
      er[0] = e0; er[1] = e1;
    }
    float w[16];
    if (wrow){
      const float4* wp = (const float4*)(wrow + k0);
      #pragma unroll
      for (int q = 0; q < 4; q++){
        float4 t = wp[q];
        w[q*4+0] = t.x; w[q*4+1] = t.y; w[q*4+2] = t.z; w[q*4+3] = t.w;
      }
    }
    __syncthreads();
    if (wrow){
      #pragma unroll
      for (int p = 0; p < TOKN; p++){
        const float4* e4 = (const float4*)&E[p][0];
        float4 ea = e4[0], eb = e4[1], ec = e4[2], ed = e4[3];
        float s = acc[p];
        s=fmaf(ea.x,w[0],s);  s=fmaf(ea.y,w[1],s);  s=fmaf(ea.z,w[2],s);  s=fmaf(ea.w,w[3],s);
        s=fmaf(eb.x,w[4],s);  s=fmaf(eb.y,w[5],s);  s=fmaf(eb.z,w[6],s);  s=fmaf(eb.w,w[7],s);
        s=fmaf(ec.x,w[8],s);  s=fmaf(ec.y,w[9],s);  s=fmaf(ec.z,w[10],s); s=fmaf(ec.w,w[11],s);
        s=fmaf(ed.x,w[12],s); s=fmaf(ed.y,w[13],s); s=fmaf(ed.z,w[14],s); s=fmaf(ed.w,w[15],s);
        acc[p] = s;
      }
    }
    __syncthreads();
  }

  // Pooling. Virtual channel layout: [0,100)=conv1; [100,200)=conv2 t0;
  // [200,300)=conv2 t1; [300,400)=conv3 t0; [400,500)=conv3 t1; [500,600)=conv3 t2.
  if (c >= 200 && c < 300){ int o = c - 200; for (int p = 0; p < TOKN; p++) stage[0][o][p] = acc[p]; }
  if (c >= 500 && c < 600){ int o = c - 500; for (int p = 0; p < TOKN; p++) stage[1][o][p] = acc[p]; }
  __syncthreads();
  if (c < 100){
    float bb = cb1[c];
    float mv = -1e30f;
    #pragma unroll
    for (int p = 0; p < 50; p++) mv = fmaxf(mv, acc[p] + bb);
    pooled[c] = fmaxf(mv, 0.f);
  }
  if (c >= 100 && c < 200){
    int o = c - 100; float bb = cb2[o];
    float mv = -1e30f;
    #pragma unroll
    for (int p = 0; p < 49; p++) mv = fmaxf(mv, acc[p] + stage[0][o][p + 1] + bb);
    pooled[100 + o] = fmaxf(mv, 0.f);
  }
  __syncthreads();
  if (c >= 400 && c < 500){ int o = c - 400; for (int p = 0; p < TOKN; p++) stage[0][o][p] = acc[p]; }
  __syncthreads();
  if (c >= 300 && c < 400){
    int o = c - 300; float bb = cb3[o];
    float mv = -1e30f;
    #pragma unroll
    for (int p = 0; p < 48; p++) mv = fmaxf(mv, acc[p] + stage[0][o][p + 1] + stage[1][o][p + 2] + bb);
    pooled[200 + o] = fmaxf(mv, 0.f);
  }
  __syncthreads();

  // FC 300 -> 512, then ln_free over the 512 outputs.
  float val = 0.f;
  if (tid < EMB){
    const float* tw = tfw + (size_t)tid * 300;
    float s = tfb[tid];
    for (int j = 0; j < 300; j++) s = fmaf(pooled[j], tw[j], s);
    val = s;
  }
  float tot = block_reduce(val, red, 10, false);
  float mu = tot * (1.f / 512.f);
  float sx = (tid < EMB) ? (val - mu) : 0.f;
  float v2 = block_reduce(sx * sx, red, 10, false);
  float var = v2 * (1.f / 512.f);
  float sc = sqrtf(1.f / (var + 1e-12f));
  if (tid < EMB) base[(size_t)r * EMB + tid] = sx * sc;
}

// ---------------------------------------------------------------------------
// Generic f32 GEMM: C[M,N] = act(A[M,K] @ W[N,K]^T + bias[N]).
// act: 0 none, 1 relu, 2 exact gelu. 64x64 tile, 256 threads, 4x4 microtile.
// ---------------------------------------------------------------------------
__global__ __launch_bounds__(256) void gemm_kernel(
    const float* __restrict__ A, const float* __restrict__ W,
    const float* __restrict__ bias, float* __restrict__ C,
    int M, int N, int K, int act)
{
  __shared__ float As[16][64];
  __shared__ float Ws[16][64];
  const int tid = threadIdx.x;
  const int m0 = blockIdx.y * 64, n0 = blockIdx.x * 64;
  const int lr = tid >> 2;
  const int lk = (tid & 3) * 4;
  const int tx = tid & 15, ty = tid >> 4;
  float cc[4][4];
  #pragma unroll
  for (int i = 0; i < 4; i++)
    #pragma unroll
    for (int j = 0; j < 4; j++) cc[i][j] = 0.f;

  for (int k0 = 0; k0 < K; k0 += 16){
    #pragma unroll
    for (int i = 0; i < 4; i++){
      int k = k0 + lk + i;
      int m = m0 + lr;
      As[lk + i][lr] = (m < M && k < K) ? A[(size_t)m * K + k] : 0.f;
      int n = n0 + lr;
      Ws[lk + i][lr] = (n < N && k < K) ? W[(size_t)n * K + k] : 0.f;
    }
    __syncthreads();
    #pragma unroll
    for (int kk = 0; kk < 16; kk++){
      float4 a = *(const float4*)&As[kk][ty * 4];
      float4 b = *(const float4*)&Ws[kk][tx * 4];
      float av[4] = {a.x, a.y, a.z, a.w};
      float bv[4] = {b.x, b.y, b.z, b.w};
      #pragma unroll
      for (int i = 0; i < 4; i++)
        #pragma unroll
        for (int j = 0; j < 4; j++) cc[i][j] = fmaf(av[i], bv[j], cc[i][j]);
    }
    __syncthreads();
  }

  #pragma unroll
  for (int i = 0; i < 4; i++){
    int m = m0 + ty * 4 + i;
    if (m >= M) continue;
    #pragma unroll
    for (int j = 0; j < 4; j++){
      int n = n0 + tx * 4 + j;
      if (n >= N) continue;
      float v = cc[i][j] + bias[n];
      if (act == 1) v = fmaxf(v, 0.f);
      else if (act == 2) v = 0.5f * v * (1.f + erff(v * 0.70710678118654752f));
      C[(size_t)m * N + n] = v;
    }
  }
}

// ---------------------------------------------------------------------------
// LayerNorm over EMB=512. Y = norm(X + Res) [*g + b] [*pscale + pbias].
// One block (256 threads, 2 elems/thread) per row.
// ---------------------------------------------------------------------------
__global__ __launch_bounds__(256) void ln_kernel(
    const float* __restrict__ X, const float* __restrict__ Res,
    const float* __restrict__ g, const float* __restrict__ bta,
    const float* __restrict__ pscale, const float* __restrict__ pbias,
    float* __restrict__ Y, int S, float eps)
{
  __shared__ float red[8];
  const int r = blockIdx.x, tid = threadIdx.x;
  size_t o0 = (size_t)r * EMB + tid;
  size_t o1 = o0 + 256;
  float v0 = X[o0] + (Res ? Res[o0] : 0.f);
  float v1 = X[o1] + (Res ? Res[o1] : 0.f);
  float tot = block_reduce(v0 + v1, red, 4, false);
  float mu = tot * (1.f / 512.f);
  float s0 = v0 - mu, s1 = v1 - mu;
  float var = block_reduce(s0 * s0 + s1 * s1, red, 4, false) * (1.f / 512.f);
  float rs = 1.f / sqrtf(var + eps);
  float y0 = s0 * rs, y1 = s1 * rs;
  if (g){
    y0 = y0 * g[tid] + bta[tid];
    y1 = y1 * g[tid + 256] + bta[tid + 256];
  }
  if (pscale){
    int b = r / S, t = r % S;
    size_t po = ((size_t)(b * 300 + t)) * EMB;
    y0 = y0 * pscale[po + tid] + pbias[po + tid];
    y1 = y1 * pscale[po + tid + 256] + pbias[po + tid + 256];
  }
  Y[o0] = y0;
  Y[o1] = y1;
}

// ---------------------------------------------------------------------------
// Fused masked attention for one (b, h, i): scores + softmax + ctx.
// Mask recomputed analytically (True => -1e9): keep iff
//   i==0  ||  (b==0 && h>=6)  ||  (h<6 && max(0,i-5) <= j <= min(S-1,i+4)).
// ---------------------------------------------------------------------------
__global__ __launch_bounds__(64) void attn_kernel(
    const float* __restrict__ Q, const float* __restrict__ Kb,
    const float* __restrict__ Vb, float* __restrict__ Ctx, int S)
{
  __shared__ float qv[DH];
  __shared__ float sc[SEQ];
  const int tid = threadIdx.x;
  const int blk = blockIdx.x;
  const int i = blk % S;
  const int bh = blk / S;
  const int h = bh % HEADS;
  const int b = bh / HEADS;
  const size_t qoff = ((size_t)(b * S + i)) * EMB + h * DH;
  qv[tid] = Q[qoff + tid];
  __syncthreads();

  const int lo = max(0, i - 5), hi = min(S - 1, i + 4);
  const bool rowall = (i == 0) || (b == 0 && h >= 6);
  for (int j = tid; j < S; j += 64){
    bool keep = rowall || (h < 6 && j >= lo && j <= hi);
    float d;
    if (keep){
      const float* kr = Kb + ((size_t)(b * S + j)) * EMB + h * DH;
      d = 0.f;
      #pragma unroll
      for (int d4 = 0; d4 < 16; d4++){
        float4 kk = *(const float4*)(kr + d4 * 4);
        d = fmaf(qv[d4*4+0], kk.x, d);
        d = fmaf(qv[d4*4+1], kk.y, d);
        d = fmaf(qv[d4*4+2], kk.z, d);
        d = fmaf(qv[d4*4+3], kk.w, d);
      }
      d *= 0.125f;
    } else {
      d = -1000000000.0f;
    }
    sc[j] = d;
  }
  __syncthreads();

  float mx = -INFINITY;
  for (int j = tid; j < S; j += 64) mx = fmaxf(mx, sc[j]);
  #pragma unroll
  for (int o = 32; o > 0; o >>= 1) mx = fmaxf(mx, __shfl_down(mx, o, 64));
  mx = __shfl(mx, 0, 64);
  float sm = 0.f;
  for (int j = tid; j < S; j += 64){ float e = expf(sc[j] - mx); sc[j] = e; sm += e; }
  #pragma unroll
  for (int o = 32; o > 0; o >>= 1) sm += __shfl_down(sm, o, 64);
  sm = __shfl(sm, 0, 64);
  float inv = 1.f / sm;
  __syncthreads();

  float a_ = 0.f;
  const float* vr = Vb + ((size_t)b * S) * EMB + h * DH + tid;
  for (int j = 0; j < S; j++) a_ = fmaf(sc[j], vr[(size_t)j * EMB], a_);
  Ctx[qoff + tid] = a_ * inv;
}

// --------------------------- small utility kernels -------------------------
__global__ void buildx1_kernel(const float* __restrict__ base, float* __restrict__ x1){
  int idx = blockIdx.x * 256 + threadIdx.x;
  if (idx >= NB * 101 * EMB) return;
  int e = idx & 511;
  int bt = idx >> 9;
  int t = bt % 101, b = bt / 101;
  x1[idx] = (t == 0) ? 0.f : base[((size_t)(b * SEQ + t - 1)) * EMB + e];
}

__global__ void extract_kernel(const float* __restrict__ p2, float* __restrict__ clsE, float* __restrict__ tok){
  int idx = blockIdx.x * 256 + threadIdx.x;
  if (idx >= NB * 101 * NCLS) return;
  int n = idx % NCLS;
  int bt = idx / NCLS;
  int t = bt % 101, b = bt / 101;
  float v = p2[idx];
  if (t == 0) clsE[b * NCLS + n] = v;
  else tok[((size_t)(b * 100 + t - 1)) * NCLS + n] = v;
}

__global__ void zero_kernel(float* p){ if (threadIdx.x == 0) p[0] = 0.f; }

// SL_hat[b,m,n] = ls[m,n] + 0.4 * sum_s P[b,s,m] P[b,s,n]
__global__ __launch_bounds__(256) void slhat_kernel(
    const float* __restrict__ P, const float* __restrict__ ls, float* __restrict__ SLh)
{
  int bm = blockIdx.x;
  int b = bm / NCLS, m = bm % NCLS;
  int n = threadIdx.x;
  if (n >= NCLS) return;
  const float* Pb = P + (size_t)b * 100 * NCLS;
  float s = 0.f;
  for (int t = 0; t < 100; t++) s = fmaf(Pb[t * NCLS + m], Pb[t * NCLS + n], s);
  SLh[((size_t)bm) * NCLS + n] = ls[m * NCLS + n] + 0.4f * s;
}

__global__ __launch_bounds__(256) void outIII_kernel(
    const float* __restrict__ cls3, const float* __restrict__ SLh, float* __restrict__ o3)
{
  int b = blockIdx.x, n = threadIdx.x;
  if (n >= NCLS) return;
  float s = 0.f;
  for (int m = 0; m < NCLS; m++)
    s = fmaf(cls3[b * NCLS + m], SLh[((size_t)(b * NCLS + m)) * NCLS + n], s);
  o3[b * NCLS + n] = s;
}

__global__ __launch_bounds__(256) void softmax_out_kernel(const float* __restrict__ X, float* __restrict__ O, int n){
  __shared__ float red[8];
  int r = blockIdx.x, tid = threadIdx.x;
  float mx = -INFINITY;
  for (int j = tid; j < n; j += 256) mx = fmaxf(mx, X[(size_t)r * n + j]);
  mx = block_reduce(mx, red, 4, true);
  float sm = 0.f;
  for (int j = tid; j < n; j += 256) sm += expf(X[(size_t)r * n + j] - mx);
  sm = block_reduce(sm, red, 4, false);
  for (int j = tid; j < n; j += 256) O[(size_t)r * n + j] = expf(X[(size_t)r * n + j] - mx) / sm;
}

// row L2-normalize: blocks 0..31 -> clsE->imn, 32..63 -> u4->sn
__global__ __launch_bounds__(256) void normalize_kernel(
    const float* __restrict__ clsE, const float* __restrict__ u4,
    float* __restrict__ imn, float* __restrict__ sn)
{
  __shared__ float red[8];
  int r = blockIdx.x, tid = threadIdx.x;
  const float* s = (r < NB) ? (clsE + (size_t)r * NCLS) : (u4 + (size_t)(r - NB) * NCLS);
  float* d = (r < NB) ? (imn + (size_t)r * NCLS) : (sn + (size_t)(r - NB) * NCLS);
  float v = (tid < NCLS) ? s[tid] : 0.f;
  float ss = block_reduce(v * v, red, 4, false);
  float nrm = fmaxf(sqrtf(ss), 1e-12f);
  if (tid < NCLS) d[tid] = v / nrm;
}

__global__ __launch_bounds__(1024) void contrastive_kernel(
    const float* __restrict__ imn, const float* __restrict__ sn, float* __restrict__ out)
{
  __shared__ float sc[NB][NB];
  __shared__ float red[16];
  int tid = threadIdx.x;
  int i = tid >> 5, j = tid & 31;
  float d = 0.f;
  for (int c = 0; c < NCLS; c++) d = fmaf(imn[i * NCLS + c], sn[j * NCLS + c], d);
  sc[i][j] = d;
  __syncthreads();
  float di = sc[i][i], dj = sc[j][j];
  float v = 0.f;
  if (i != j)
    v = fmaxf(0.02f + sc[i][j] - di, 0.f) + fmaxf(0.02f + sc[i][j] - dj, 0.f);
  #pragma unroll
  for (int o = 32; o > 0; o >>= 1) v += __shfl_down(v, o, 64);
  if ((tid & 63) == 0) red[tid >> 6] = v;
  __syncthreads();
  if (tid == 0){
    float s = 0.f;
    for (int w = 0; w < 16; w++) s += red[w];
    out[13057] = s * 0.01f;
  }
}

// means over the reference's exact slices: i=0 -> rows [0,100); i=1 -> rows [1,200)
__global__ __launch_bounds__(256) void means_kernel(
    const float* __restrict__ p1, const float* __restrict__ ap,
    float* __restrict__ mp, float* __restrict__ ma)
{
  int bi = blockIdx.x;
  int b = bi >> 1, i = bi & 1;
  int start = i;
  int cnt = (i == 0) ? 100 : 199;
  float icnt = 1.f / (float)cnt;
  for (int c = threadIdx.x; c < NCLS + EMB; c += 256){
    float s = 0.f;
    if (c < NCLS){
      for (int rr = 0; rr < cnt; rr++) s += p1[((size_t)(b * SEQ + start + rr)) * NCLS + c];
      mp[(size_t)bi * NCLS + c] = s * icnt;
    } else {
      int cc = c - NCLS;
      for (int rr = 0; rr < cnt; rr++) s += ap[((size_t)(b * SEQ + start + rr)) * EMB + cc];
      ma[(size_t)bi * EMB + cc] = s * icnt;
    }
  }
}

__global__ __launch_bounds__(64) void klfinal_kernel(
    const float* __restrict__ cbuf, const float* __restrict__ abuf, float* __restrict__ acc)
{
  const int b = blockIdx.x, lane = threadIdx.x;
  float rk[4], re[4];
  #pragma unroll
  for (int pr = 0; pr < 4; pr++){
    int i = pr >> 1, j = pr & 1;
    const float* c1 = cbuf + ((size_t)(b * 2 + i)) * NCLS;
    const float* c2 = cbuf + ((size_t)(b * 2 + j)) * NCLS;
    float s = 0.f;
    for (int n = lane; n < NCLS; n += 64){
      float x = c1[n] + 1e-6f, y = c2[n] + 1e-6f;
      s += x * logf(x / y);
    }
    #pragma unroll
    for (int o = 32; o > 0; o >>= 1) s += __shfl_down(s, o, 64);
    rk[pr] = __shfl(s, 0, 64);
    const float* a1 = abuf + ((size_t)(b * 2 + i)) * EMB;
    const float* a2 = abuf + ((size_t)(b * 2 + j)) * EMB;
    float s2 = 0.f;
    for (int n = lane; n < EMB; n += 64){
      float dd = a1[n] - a2[n];
      s2 += dd * dd;
    }
    #pragma unroll
    for (int o = 32; o > 0; o >>= 1) s2 += __shfl_down(s2, o, 64);
    re[pr] = sqrtf(__shfl(s2, 0, 64) + 1e-12f);
  }
  if (lane == 0){
    float sk[4], se[4];
    float mk = -INFINITY, me = -INFINITY;
    for (int p = 0; p < 4; p++){
      sk[p] = rk[p] * 10.f;
      mk = fmaxf(mk, sk[p]);
      se[p] = re[p];
      me = fmaxf(me, se[p]);
    }
    float ssk = 0.f, sse = 0.f;
    for (int p = 0; p < 4; p++){ sk[p] = expf(sk[p] - mk); ssk += sk[p]; se[p] = expf(se[p] - me); sse += se[p]; }
    float loss = 0.f;
    for (int p = 0; p < 4; p++){
      float x = sk[p] / ssk + 1e-6f, y = se[p] / sse + 1e-6f;
      loss += x * logf(x / y);
    }
    atomicAdd(acc, loss);
  }
}

__global__ void finalize_kernel(const float* __restrict__ acc, float* __restrict__ out){
  if (threadIdx.x == 0) out[13056] = acc[0] * (100000.f / 32.f);
}

// ---------------------------------------------------------------------------
extern "C" void kernel_launch(void* const* d_in, const int* in_sizes, int n_in,
                              void* d_out, int out_size, void* d_ws, size_t ws_size,
                              hipStream_t stream)
{
  (void)in_sizes; (void)n_in; (void)out_size; (void)ws_size;
  const int*   src  = (const int*)  d_in[0];
  const float* user_info = (const float*)d_in[1];
  const float* ls   = (const float*)d_in[2];
  const float* emb  = (const float*)d_in[3];
  const float* cw1  = (const float*)d_in[4];  const float* cb1 = (const float*)d_in[5];
  const float* cw2  = (const float*)d_in[6];  const float* cb2 = (const float*)d_in[7];
  const float* cw3  = (const float*)d_in[8];  const float* cb3 = (const float*)d_in[9];
  const float* tfw  = (const float*)d_in[10]; const float* tfb = (const float*)d_in[11];
  const float* wq   = (const float*)d_in[12]; const float* bq  = (const float*)d_in[13];
  const float* wk   = (const float*)d_in[14]; const float* bk  = (const float*)d_in[15];
  const float* wv   = (const float*)d_in[16]; const float* bv  = (const float*)d_in[17];
  const float* wo   = (const float*)d_in[18]; const float* bo  = (const float*)d_in[19];
  const float* l1g  = (const float*)d_in[20]; const float* l1b = (const float*)d_in[21];
  const float* fw1  = (const float*)d_in[22]; const float* fb1 = (const float*)d_in[23];
  const float* fw2  = (const float*)d_in[24]; const float* fb2 = (const float*)d_in[25];
  const float* l2g  = (const float*)d_in[26]; const float* l2b = (const float*)d_in[27];
  const float* fc1w = (const float*)d_in[28]; const float* fc1b= (const float*)d_in[29];
  const float* fc2w = (const float*)d_in[30]; const float* fc2b= (const float*)d_in[31];
  const float* fc3w = (const float*)d_in[32]; const float* fc3b= (const float*)d_in[33];
  const float* fc4w = (const float*)d_in[34]; const float* fc4b= (const float*)d_in[35];
  const float* pscale = (const float*)d_in[36];
  const float* pbias  = (const float*)d_in[37];
  float* out = (float*)d_out;
  float* ws = (float*)d_ws;

  size_t off = 0;
  auto alloc = [&](size_t n){ float* p = ws + off; off += ((n + 3) & ~(size_t)3); return p; };
  float* base = alloc(6400ULL * EMB);          // textcnn output / branch-2 x (in place)
  float* x1   = alloc((size_t)NB * 101 * EMB); // branch-1 x
  float* qb   = alloc(6400ULL * EMB);
  float* kb   = alloc(6400ULL * EMB);
  float* vb   = alloc(6400ULL * EMB);
  float* ctx  = alloc(6400ULL * EMB);          // also reused as gelu/ln_free activation
  float* proj = alloc(6400ULL * EMB);
  float* hb   = alloc(6400ULL * FFND);
  float* p2   = alloc(6400ULL * NCLS);         // fc2 output (p / p1)
  float* clsE = alloc((size_t)NB * NCLS);
  float* tok  = alloc(3200ULL * NCLS);
  float* Pb   = alloc(3200ULL * NCLS);
  float* cls3 = alloc((size_t)NB * NCLS);
  float* SLh  = alloc((size_t)NB * NCLS * NCLS);
  float* o3   = alloc((size_t)NB * NCLS);
  float* u4   = alloc((size_t)NB * NCLS);
  float* imn  = alloc((size_t)NB * NCLS);
  float* sn   = alloc((size_t)NB * NCLS);
  float* mp   = alloc(64ULL * NCLS);
  float* ma   = alloc(64ULL * EMB);
  float* cbf  = alloc(64ULL * NCLS);
  float* abf  = alloc(64ULL * EMB);
  float* lacc = alloc(4);
  // total ~154 MB of f32 workspace

  auto gemm = [&](const float* A, const float* W, const float* bi, float* C,
                  int M, int N, int K, int act){
    dim3 g((N + 63) / 64, (M + 63) / 64);
    gemm_kernel<<<g, 256, 0, stream>>>(A, W, bi, C, M, N, K, act);
  };

  // Stage 1: textcnn for all 6400 rows (+ per-row ln_free)
  textcnn_kernel<<<6400, 640, 0, stream>>>(src, emb, cw1, cb1, cw2, cb2, cw3, cb3, tfw, tfb, base);
  buildx1_kernel<<<(NB * 101 * EMB + 255) / 256, 256, 0, stream>>>(base, x1);

  auto encoder = [&](float* x, int S){
    int M = NB * S;
    for (int l = 0; l < NLAYERS; l++){
      gemm(x, wq + (size_t)l * EMB * EMB, bq + l * EMB, qb, M, EMB, EMB, 0);
      gemm(x, wk + (size_t)l * EMB * EMB, bk + l * EMB, kb, M, EMB, EMB, 0);
      gemm(x, wv + (size_t)l * EMB * EMB, bv + l * EMB, vb, M, EMB, EMB, 0);
      attn_kernel<<<NB * HEADS * S, 64, 0, stream>>>(qb, kb, vb, ctx, S);
      gemm(ctx, wo + (size_t)l * EMB * EMB, bo + l * EMB, proj, M, EMB, EMB, 0);
      ln_kernel<<<M, 256, 0, stream>>>(proj, x, l1g + l * EMB, l1b + l * EMB, nullptr, nullptr, x, S, 1e-5f);
      gemm(x, fw1 + (size_t)l * FFND * EMB, fb1 + l * FFND, hb, M, FFND, EMB, 1);
      gemm(hb, fw2 + (size_t)l * EMB * FFND, fb2 + l * EMB, proj, M, EMB, FFND, 0);
      ln_kernel<<<M, 256, 0, stream>>>(proj, x, l2g + l * EMB, l2b + l * EMB, nullptr, nullptr, x, S, 1e-5f);
    }
    gemm(x, fc1w, fc1b, ctx, M, EMB, EMB, 2);                                   // gelu
    ln_kernel<<<M, 256, 0, stream>>>(ctx, nullptr, nullptr, nullptr, pscale, pbias, ctx, S, 1e-12f);
    gemm(ctx, fc2w, fc2b, p2, M, NCLS, EMB, 0);
  };

  // Branch 1: S=101
  encoder(x1, 101);
  extract_kernel<<<(NB * 101 * NCLS + 255) / 256, 256, 0, stream>>>(p2, clsE, tok);
  gemm(tok, fc3w, fc3b, Pb, 3200, NCLS, NCLS, 0);
  gemm(clsE, fc3w, fc3b, cls3, NB, NCLS, NCLS, 0);
  slhat_kernel<<<NB * NCLS, 256, 0, stream>>>(Pb, ls, SLh);
  outIII_kernel<<<NB, 256, 0, stream>>>(cls3, SLh, o3);
  softmax_out_kernel<<<NB, 256, 0, stream>>>(o3, out, NCLS);                    // output 0
  softmax_out_kernel<<<NB, 256, 0, stream>>>(clsE, out + NB * NCLS, NCLS);      // output 1
  gemm(user_info, fc4w, fc4b, u4, NB, NCLS, 142, 0);
  normalize_kernel<<<64, 256, 0, stream>>>(clsE, u4, imn, sn);
  contrastive_kernel<<<1, 1024, 0, stream>>>(imn, sn, out);                     // output 3

  // Branch 2: S=200 (in place on base); ctx ends as ap_final, p2 as p1
  encoder(base, SEQ);
  zero_kernel<<<1, 64, 0, stream>>>(lacc);
  means_kernel<<<64, 256, 0, stream>>>(p2, ctx, mp, ma);
  softmax_out_kernel<<<64, 256, 0, stream>>>(mp, cbf, NCLS);
  softmax_out_kernel<<<64, 256, 0, stream>>>(ma, abf, EMB);
  klfinal_kernel<<<NB, 64, 0, stream>>>(cbf, abf, lacc);
  finalize_kernel<<<1, 64, 0, stream>>>(lacc, out);                             // output 2
}

// Round 3
// 12134.915 us; speedup vs baseline: 1.8678x; 1.8678x over previous
//
#include <hip/hip_runtime.h>
#include <math.h>

#define EMB 512
#define HEADS 8
#define NLAYERS 4
#define NB 32
#define SEQ 200
#define TOKN 50
#define DH 64
#define FFND 2048
#define NCLS 204
#define VC 640          // virtual conv channels, padded (600 real)
#define KD 1024         // conv K dim

typedef __attribute__((ext_vector_type(8))) short v8s;   // 8 bf16 in 4 VGPRs
typedef __attribute__((ext_vector_type(4))) float v4f;

__device__ __forceinline__ unsigned short f2bu(float f){  // f32 -> bf16 bits, RNE
  unsigned u = __float_as_uint(f);
  return (unsigned short)((u + 0x7FFFu + ((u >> 16) & 1u)) >> 16);
}
__device__ __forceinline__ float bu2f(unsigned short u){
  return __uint_as_float(((unsigned)u) << 16);
}

// Block reduction: sum or max across the whole block. Identity must be fed by
// threads with no data (0 for sum, -INF for max). Call from uniform control flow.
__device__ __forceinline__ float block_reduce(float v, float* red, int nwaves, bool domax){
  int tid = threadIdx.x;
  #pragma unroll
  for (int o = 32; o > 0; o >>= 1){
    float t = __shfl_down(v, o, 64);
    v = domax ? fmaxf(v, t) : (v + t);
  }
  __syncthreads();                 // protect red from previous use
  if ((tid & 63) == 0) red[tid >> 6] = v;
  __syncthreads();
  float r = red[0];
  for (int i = 1; i < nwaves; i++) r = domax ? fmaxf(r, red[i]) : (r + red[i]);
  return r;
}

// ---------------------------------------------------------------------------
// Prep: pack conv weights into bf16 virtual-channel layout Wb[VC][KD].
// vchan: [0,100)=conv1; [100,200)=c2 tap0; [200,300)=c2 tap1;
//        [300,400)=c3 tap0; [400,500)=c3 tap1; [500,600)=c3 tap2; [600,640)=0.
// ---------------------------------------------------------------------------
__global__ void prep_w_kernel(const float* __restrict__ cw1, const float* __restrict__ cw2,
                              const float* __restrict__ cw3, unsigned short* __restrict__ Wb){
  int idx4 = blockIdx.x * 256 + threadIdx.x;       // one ushort4 (4 elems) each
  if (idx4 >= VC * KD / 4) return;
  int row = idx4 >> 8;                             // KD/4 = 256 quads per row
  int k = (idx4 & 255) * 4;
  float4 v = make_float4(0.f, 0.f, 0.f, 0.f);
  const float* s = nullptr;
  if (row < 100)      s = cw1 + (size_t)row * KD;
  else if (row < 200) s = cw2 + (size_t)((row - 100) * 2 + 0) * KD;
  else if (row < 300) s = cw2 + (size_t)((row - 200) * 2 + 1) * KD;
  else if (row < 400) s = cw3 + (size_t)((row - 300) * 3 + 0) * KD;
  else if (row < 500) s = cw3 + (size_t)((row - 400) * 3 + 1) * KD;
  else if (row < 600) s = cw3 + (size_t)((row - 500) * 3 + 2) * KD;
  if (s) v = *(const float4*)(s + k);
  ushort4 o;
  o.x = f2bu(v.x); o.y = f2bu(v.y); o.z = f2bu(v.z); o.w = f2bu(v.w);
  *(ushort4*)(Wb + (size_t)row * KD + k) = o;
}

// Prep: transpose tfw (512x300) -> tfwT (300x512) for coalesced FC reads.
__global__ void prep_tfwT_kernel(const float* __restrict__ tfw, float* __restrict__ tfwT){
  int idx = blockIdx.x * 256 + threadIdx.x;
  if (idx >= 300 * EMB) return;
  int j = idx >> 9, o = idx & 511;
  tfwT[(size_t)j * EMB + o] = tfw[(size_t)o * 300 + j];
}

// ---------------------------------------------------------------------------
// TextCNN via MFMA: one block per sequence row. GEMM C[64 pos][640 vch] =
// E(bf16) @ Wb(bf16)^T with f32 accum; then pool(+bias,relu) -> FC 300->512
// -> ln_free, all in-block. 256 threads = 4 waves; wave = 2 M-tiles x 20
// N-tiles (16x16x32 MFMA), giving 22 ds_read_b128 per 40 MFMA (m97 ratio).
// ---------------------------------------------------------------------------
__global__ __launch_bounds__(256, 2) void textcnn_mfma_kernel(
    const int* __restrict__ src, const float* __restrict__ emb,
    const unsigned short* __restrict__ Wb, const float* __restrict__ tfwT,
    const float* __restrict__ cb1, const float* __restrict__ cb2,
    const float* __restrict__ cb3, const float* __restrict__ tfb,
    float* __restrict__ base)
{
  // union region: GEMM staging (A 64x40 + W 640x40 bf16 = 56.3 KB) vs
  // conv-out stage Sg[640][52] bf16 = 66.6 KB  -> 66.6 KB
  __shared__ __align__(16) char smem[66560];
  __shared__ float pooled[304];
  __shared__ float red[8];
  __shared__ int toks[TOKN];

  unsigned short (*Al)[40] = (unsigned short(*)[40])smem;            // [64][40], +8 pad kills LDS conflicts
  unsigned short (*Wl)[40] = (unsigned short(*)[40])(smem + 5120);   // [640][40]
  unsigned short (*Sg)[52] = (unsigned short(*)[52])smem;            // [640][52]

  const int tid = threadIdx.x;
  const int r = blockIdx.x;
  if (tid < TOKN) toks[tid] = src[r * TOKN + tid];
  __syncthreads();

  const int lane = tid & 63;
  const int wave = tid >> 6;
  const int mh = wave >> 1;          // M half (0..1): 32 positions
  const int nh = wave & 1;           // N half (0..1): 320 channels
  const int lcol = lane & 15;
  const int lq   = lane >> 4;

  v4f acc[2][20];
  #pragma unroll
  for (int mi = 0; mi < 2; mi++)
    #pragma unroll
    for (int ni = 0; ni < 20; ni++) acc[mi][ni] = (v4f){0.f, 0.f, 0.f, 0.f};

  // A-staging assignment: thread stages 8 k-elems of one position
  const int ap = tid >> 2;            // 0..63 (position)
  const int ak = (tid & 3) * 8;       // k offset in chunk
  const float* aep = (ap < TOKN) ? (emb + (size_t)toks[ap] * KD + ak) : nullptr;

  for (int kc = 0; kc < KD / 32; kc++){
    { // stage A (f32 -> bf16 on the fly)
      uint4 pk = make_uint4(0, 0, 0, 0);
      if (aep){
        float4 f0 = *(const float4*)(aep + kc * 32);
        float4 f1 = *(const float4*)(aep + kc * 32 + 4);
        pk.x = (unsigned)f2bu(f0.x) | ((unsigned)f2bu(f0.y) << 16);
        pk.y = (unsigned)f2bu(f0.z) | ((unsigned)f2bu(f0.w) << 16);
        pk.z = (unsigned)f2bu(f1.x) | ((unsigned)f2bu(f1.y) << 16);
        pk.w = (unsigned)f2bu(f1.z) | ((unsigned)f2bu(f1.w) << 16);
      }
      *(uint4*)&Al[ap][ak] = pk;
    }
    // stage W chunk: 640 rows x 32 k = 2560 uint4s, 10 per thread
    #pragma unroll
    for (int i = 0; i < 10; i++){
      int idx = tid + 256 * i;
      int row = idx >> 2;
      int kq = (idx & 3) * 8;
      uint4 w = *(const uint4*)(Wb + (size_t)row * KD + kc * 32 + kq);
      *(uint4*)&Wl[row][kq] = w;
    }
    __syncthreads();
    v8s af[2];
    #pragma unroll
    for (int mi = 0; mi < 2; mi++)
      af[mi] = *(const v8s*)&Al[mh * 32 + mi * 16 + lcol][lq * 8];
    #pragma unroll
    for (int ni = 0; ni < 20; ni++){
      v8s bf = *(const v8s*)&Wl[nh * 320 + ni * 16 + lcol][lq * 8];
      acc[0][ni] = __builtin_amdgcn_mfma_f32_16x16x32_bf16(af[0], bf, acc[0][ni], 0, 0, 0);
      acc[1][ni] = __builtin_amdgcn_mfma_f32_16x16x32_bf16(af[1], bf, acc[1][ni], 0, 0, 0);
    }
    __syncthreads();
  }

  // stage conv outputs to Sg (bf16). C layout: col=lane&15, row=lq*4+reg.
  #pragma unroll
  for (int mi = 0; mi < 2; mi++){
    #pragma unroll
    for (int ni = 0; ni < 20; ni++){
      int ch = nh * 320 + ni * 16 + lcol;
      #pragma unroll
      for (int rg = 0; rg < 4; rg++){
        int pos = mh * 32 + mi * 16 + lq * 4 + rg;
        if (pos < TOKN) Sg[ch][pos] = f2bu(acc[mi][ni][rg]);
      }
    }
  }
  __syncthreads();

  // pooling: max over positions of shifted vchan sums, + bias, relu
  for (int c = tid; c < 300; c += 256){
    float mv = -1e30f;
    if (c < 100){
      float bb = cb1[c];
      for (int p = 0; p < 50; p++) mv = fmaxf(mv, bu2f(Sg[c][p]) + bb);
    } else if (c < 200){
      int o = c - 100; float bb = cb2[o];
      for (int p = 0; p < 49; p++)
        mv = fmaxf(mv, bu2f(Sg[100 + o][p]) + bu2f(Sg[200 + o][p + 1]) + bb);
    } else {
      int o = c - 200; float bb = cb3[o];
      for (int p = 0; p < 48; p++)
        mv = fmaxf(mv, bu2f(Sg[300 + o][p]) + bu2f(Sg[400 + o][p + 1]) + bu2f(Sg[500 + o][p + 2]) + bb);
    }
    pooled[c] = fmaxf(mv, 0.f);
  }
  __syncthreads();

  // FC 300 -> 512 (f32, coalesced via tfwT) + ln_free
  float v0 = tfb[tid], v1 = tfb[tid + 256];
  for (int j = 0; j < 300; j++){
    float pj = pooled[j];
    v0 = fmaf(pj, tfwT[(size_t)j * EMB + tid], v0);
    v1 = fmaf(pj, tfwT[(size_t)j * EMB + tid + 256], v1);
  }
  float tot = block_reduce(v0 + v1, red, 4, false);
  float mu = tot * (1.f / 512.f);
  float s0 = v0 - mu, s1 = v1 - mu;
  float var = block_reduce(s0 * s0 + s1 * s1, red, 4, false) * (1.f / 512.f);
  float sc = sqrtf(1.f / (var + 1e-12f));
  base[(size_t)r * EMB + tid] = s0 * sc;
  base[(size_t)r * EMB + tid + 256] = s1 * sc;
}

// ---------------------------------------------------------------------------
// Generic f32 GEMM: C[M,N] = act(A[M,K] @ W[N,K]^T + bias[N]).
// act: 0 none, 1 relu, 2 exact gelu. 64x64 tile, 256 threads, 4x4 microtile.
// ---------------------------------------------------------------------------
__global__ __launch_bounds__(256) void gemm_kernel(
    const float* __restrict__ A, const float* __restrict__ W,
    const float* __restrict__ bias, float* __restrict__ C,
    int M, int N, int K, int act)
{
  __shared__ float As[16][64];
  __shared__ float Ws[16][64];
  const int tid = threadIdx.x;
  const int m0 = blockIdx.y * 64, n0 = blockIdx.x * 64;
  const int lr = tid >> 2;
  const int lk = (tid & 3) * 4;
  const int tx = tid & 15, ty = tid >> 4;
  float cc[4][4];
  #pragma unroll
  for (int i = 0; i < 4; i++)
    #pragma unroll
    for (int j = 0; j < 4; j++) cc[i][j] = 0.f;

  for (int k0 = 0; k0 < K; k0 += 16){
    #pragma unroll
    for (int i = 0; i < 4; i++){
      int k = k0 + lk + i;
      int m = m0 + lr;
      As[lk + i][lr] = (m < M && k < K) ? A[(size_t)m * K + k] : 0.f;
      int n = n0 + lr;
      Ws[lk + i][lr] = (n < N && k < K) ? W[(size_t)n * K + k] : 0.f;
    }
    __syncthreads();
    #pragma unroll
    for (int kk = 0; kk < 16; kk++){
      float4 a = *(const float4*)&As[kk][ty * 4];
      float4 b = *(const float4*)&Ws[kk][tx * 4];
      float av[4] = {a.x, a.y, a.z, a.w};
      float bv[4] = {b.x, b.y, b.z, b.w};
      #pragma unroll
      for (int i = 0; i < 4; i++)
        #pragma unroll
        for (int j = 0; j < 4; j++) cc[i][j] = fmaf(av[i], bv[j], cc[i][j]);
    }
    __syncthreads();
  }

  #pragma unroll
  for (int i = 0; i < 4; i++){
    int m = m0 + ty * 4 + i;
    if (m >= M) continue;
    #pragma unroll
    for (int j = 0; j < 4; j++){
      int n = n0 + tx * 4 + j;
      if (n >= N) continue;
      float v = cc[i][j] + bias[n];
      if (act == 1) v = fmaxf(v, 0.f);
      else if (act == 2) v = 0.5f * v * (1.f + erff(v * 0.70710678118654752f));
      C[(size_t)m * N + n] = v;
    }
  }
}

// ---------------------------------------------------------------------------
// LayerNorm over EMB=512. Y = norm(X + Res) [*g + b] [*pscale + pbias].
// One block (256 threads, 2 elems/thread) per row.
// ---------------------------------------------------------------------------
__global__ __launch_bounds__(256) void ln_kernel(
    const float* __restrict__ X, const float* __restrict__ Res,
    const float* __restrict__ g, const float* __restrict__ bta,
    const float* __restrict__ pscale, const float* __restrict__ pbias,
    float* __restrict__ Y, int S, float eps)
{
  __shared__ float red[8];
  const int r = blockIdx.x, tid = threadIdx.x;
  size_t o0 = (size_t)r * EMB + tid;
  size_t o1 = o0 + 256;
  float v0 = X[o0] + (Res ? Res[o0] : 0.f);
  float v1 = X[o1] + (Res ? Res[o1] : 0.f);
  float tot = block_reduce(v0 + v1, red, 4, false);
  float mu = tot * (1.f / 512.f);
  float s0 = v0 - mu, s1 = v1 - mu;
  float var = block_reduce(s0 * s0 + s1 * s1, red, 4, false) * (1.f / 512.f);
  float rs = 1.f / sqrtf(var + eps);
  float y0 = s0 * rs, y1 = s1 * rs;
  if (g){
    y0 = y0 * g[tid] + bta[tid];
    y1 = y1 * g[tid + 256] + bta[tid + 256];
  }
  if (pscale){
    int b = r / S, t = r % S;
    size_t po = ((size_t)(b * 300 + t)) * EMB;
    y0 = y0 * pscale[po + tid] + pbias[po + tid];
    y1 = y1 * pscale[po + tid + 256] + pbias[po + tid + 256];
  }
  Y[o0] = y0;
  Y[o1] = y1;
}

// ---------------------------------------------------------------------------
// Fused masked attention for one (b, h, i): scores + softmax + ctx.
// Mask recomputed analytically (True => -1e9): keep iff
//   i==0  ||  (b==0 && h>=6)  ||  (h<6 && max(0,i-5) <= j <= min(S-1,i+4)).
// ---------------------------------------------------------------------------
__global__ __launch_bounds__(64) void attn_kernel(
    const float* __restrict__ Q, const float* __restrict__ Kb,
    const float* __restrict__ Vb, float* __restrict__ Ctx, int S)
{
  __shared__ float qv[DH];
  __shared__ float sc[SEQ];
  const int tid = threadIdx.x;
  const int blk = blockIdx.x;
  const int i = blk % S;
  const int bh = blk / S;
  const int h = bh % HEADS;
  const int b = bh / HEADS;
  const size_t qoff = ((size_t)(b * S + i)) * EMB + h * DH;
  qv[tid] = Q[qoff + tid];
  __syncthreads();

  const int lo = max(0, i - 5), hi = min(S - 1, i + 4);
  const bool rowall = (i == 0) || (b == 0 && h >= 6);
  for (int j = tid; j < S; j += 64){
    bool keep = rowall || (h < 6 && j >= lo && j <= hi);
    float d;
    if (keep){
      const float* kr = Kb + ((size_t)(b * S + j)) * EMB + h * DH;
      d = 0.f;
      #pragma unroll
      for (int d4 = 0; d4 < 16; d4++){
        float4 kk = *(const float4*)(kr + d4 * 4);
        d = fmaf(qv[d4*4+0], kk.x, d);
        d = fmaf(qv[d4*4+1], kk.y, d);
        d = fmaf(qv[d4*4+2], kk.z, d);
        d = fmaf(qv[d4*4+3], kk.w, d);
      }
      d *= 0.125f;
    } else {
      d = -1000000000.0f;
    }
    sc[j] = d;
  }
  __syncthreads();

  float mx = -INFINITY;
  for (int j = tid; j < S; j += 64) mx = fmaxf(mx, sc[j]);
  #pragma unroll
  for (int o = 32; o > 0; o >>= 1) mx = fmaxf(mx, __shfl_down(mx, o, 64));
  mx = __shfl(mx, 0, 64);
  float sm = 0.f;
  for (int j = tid; j < S; j += 64){ float e = expf(sc[j] - mx); sc[j] = e; sm += e; }
  #pragma unroll
  for (int o = 32; o > 0; o >>= 1) sm += __shfl_down(sm, o, 64);
  sm = __shfl(sm, 0, 64);
  float inv = 1.f / sm;
  __syncthreads();

  float a_ = 0.f;
  const float* vr = Vb + ((size_t)b * S) * EMB + h * DH + tid;
  for (int j = 0; j < S; j++) a_ = fmaf(sc[j], vr[(size_t)j * EMB], a_);
  Ctx[qoff + tid] = a_ * inv;
}

// --------------------------- small utility kernels -------------------------
__global__ void buildx1_kernel(const float* __restrict__ base, float* __restrict__ x1){
  int idx = blockIdx.x * 256 + threadIdx.x;
  if (idx >= NB * 101 * EMB) return;
  int e = idx & 511;
  int bt = idx >> 9;
  int t = bt % 101, b = bt / 101;
  x1[idx] = (t == 0) ? 0.f : base[((size_t)(b * SEQ + t - 1)) * EMB + e];
}

__global__ void extract_kernel(const float* __restrict__ p2, float* __restrict__ clsE, float* __restrict__ tok){
  int idx = blockIdx.x * 256 + threadIdx.x;
  if (idx >= NB * 101 * NCLS) return;
  int n = idx % NCLS;
  int bt = idx / NCLS;
  int t = bt % 101, b = bt / 101;
  float v = p2[idx];
  if (t == 0) clsE[b * NCLS + n] = v;
  else tok[((size_t)(b * 100 + t - 1)) * NCLS + n] = v;
}

__global__ void zero_kernel(float* p){ if (threadIdx.x == 0) p[0] = 0.f; }

// SL_hat[b,m,n] = ls[m,n] + 0.4 * sum_s P[b,s,m] P[b,s,n]
__global__ __launch_bounds__(256) void slhat_kernel(
    const float* __restrict__ P, const float* __restrict__ ls, float* __restrict__ SLh)
{
  int bm = blockIdx.x;
  int b = bm / NCLS, m = bm % NCLS;
  int n = threadIdx.x;
  if (n >= NCLS) return;
  const float* Pb = P + (size_t)b * 100 * NCLS;
  float s = 0.f;
  for (int t = 0; t < 100; t++) s = fmaf(Pb[t * NCLS + m], Pb[t * NCLS + n], s);
  SLh[((size_t)bm) * NCLS + n] = ls[m * NCLS + n] + 0.4f * s;
}

__global__ __launch_bounds__(256) void outIII_kernel(
    const float* __restrict__ cls3, const float* __restrict__ SLh, float* __restrict__ o3)
{
  int b = blockIdx.x, n = threadIdx.x;
  if (n >= NCLS) return;
  float s = 0.f;
  for (int m = 0; m < NCLS; m++)
    s = fmaf(cls3[b * NCLS + m], SLh[((size_t)(b * NCLS + m)) * NCLS + n], s);
  o3[b * NCLS + n] = s;
}

__global__ __launch_bounds__(256) void softmax_out_kernel(const float* __restrict__ X, float* __restrict__ O, int n){
  __shared__ float red[8];
  int r = blockIdx.x, tid = threadIdx.x;
  float mx = -INFINITY;
  for (int j = tid; j < n; j += 256) mx = fmaxf(mx, X[(size_t)r * n + j]);
  mx = block_reduce(mx, red, 4, true);
  float sm = 0.f;
  for (int j = tid; j < n; j += 256) sm += expf(X[(size_t)r * n + j] - mx);
  sm = block_reduce(sm, red, 4, false);
  for (int j = tid; j < n; j += 256) O[(size_t)r * n + j] = expf(X[(size_t)r * n + j] - mx) / sm;
}

// row L2-normalize: blocks 0..31 -> clsE->imn, 32..63 -> u4->sn
__global__ __launch_bounds__(256) void normalize_kernel(
    const float* __restrict__ clsE, const float* __restrict__ u4,
    float* __restrict__ imn, float* __restrict__ sn)
{
  __shared__ float red[8];
  int r = blockIdx.x, tid = threadIdx.x;
  const float* s = (r < NB) ? (clsE + (size_t)r * NCLS) : (u4 + (size_t)(r - NB) * NCLS);
  float* d = (r < NB) ? (imn + (size_t)r * NCLS) : (sn + (size_t)(r - NB) * NCLS);
  float v = (tid < NCLS) ? s[tid] : 0.f;
  float ss = block_reduce(v * v, red, 4, false);
  float nrm = fmaxf(sqrtf(ss), 1e-12f);
  if (tid < NCLS) d[tid] = v / nrm;
}

__global__ __launch_bounds__(1024) void contrastive_kernel(
    const float* __restrict__ imn, const float* __restrict__ sn, float* __restrict__ out)
{
  __shared__ float sc[NB][NB];
  __shared__ float red[16];
  int tid = threadIdx.x;
  int i = tid >> 5, j = tid & 31;
  float d = 0.f;
  for (int c = 0; c < NCLS; c++) d = fmaf(imn[i * NCLS + c], sn[j * NCLS + c], d);
  sc[i][j] = d;
  __syncthreads();
  float di = sc[i][i], dj = sc[j][j];
  float v = 0.f;
  if (i != j)
    v = fmaxf(0.02f + sc[i][j] - di, 0.f) + fmaxf(0.02f + sc[i][j] - dj, 0.f);
  #pragma unroll
  for (int o = 32; o > 0; o >>= 1) v += __shfl_down(v, o, 64);
  if ((tid & 63) == 0) red[tid >> 6] = v;
  __syncthreads();
  if (tid == 0){
    float s = 0.f;
    for (int w = 0; w < 16; w++) s += red[w];
    out[13057] = s * 0.01f;
  }
}

// means over the reference's exact slices: i=0 -> rows [0,100); i=1 -> rows [1,200)
__global__ __launch_bounds__(256) void means_kernel(
    const float* __restrict__ p1, const float* __restrict__ ap,
    float* __restrict__ mp, float* __restrict__ ma)
{
  int bi = blockIdx.x;
  int b = bi >> 1, i = bi & 1;
  int start = i;
  int cnt = (i == 0) ? 100 : 199;
  float icnt = 1.f / (float)cnt;
  for (int c = threadIdx.x; c < NCLS + EMB; c += 256){
    float s = 0.f;
    if (c < NCLS){
      for (int rr = 0; rr < cnt; rr++) s += p1[((size_t)(b * SEQ + start + rr)) * NCLS + c];
      mp[(size_t)bi * NCLS + c] = s * icnt;
    } else {
      int cc = c - NCLS;
      for (int rr = 0; rr < cnt; rr++) s += ap[((size_t)(b * SEQ + start + rr)) * EMB + cc];
      ma[(size_t)bi * EMB + cc] = s * icnt;
    }
  }
}

__global__ __launch_bounds__(64) void klfinal_kernel(
    const float* __restrict__ cbuf, const float* __restrict__ abuf, float* __restrict__ acc)
{
  const int b = blockIdx.x, lane = threadIdx.x;
  float rk[4], re[4];
  #pragma unroll
  for (int pr = 0; pr < 4; pr++){
    int i = pr >> 1, j = pr & 1;
    const float* c1 = cbuf + ((size_t)(b * 2 + i)) * NCLS;
    const float* c2 = cbuf + ((size_t)(b * 2 + j)) * NCLS;
    float s = 0.f;
    for (int n = lane; n < NCLS; n += 64){
      float x = c1[n] + 1e-6f, y = c2[n] + 1e-6f;
      s += x * logf(x / y);
    }
    #pragma unroll
    for (int o = 32; o > 0; o >>= 1) s += __shfl_down(s, o, 64);
    rk[pr] = __shfl(s, 0, 64);
    const float* a1 = abuf + ((size_t)(b * 2 + i)) * EMB;
    const float* a2 = abuf + ((size_t)(b * 2 + j)) * EMB;
    float s2 = 0.f;
    for (int n = lane; n < EMB; n += 64){
      float dd = a1[n] - a2[n];
      s2 += dd * dd;
    }
    #pragma unroll
    for (int o = 32; o > 0; o >>= 1) s2 += __shfl_down(s2, o, 64);
    re[pr] = sqrtf(__shfl(s2, 0, 64) + 1e-12f);
  }
  if (lane == 0){
    float sk[4], se[4];
    float mk = -INFINITY, me = -INFINITY;
    for (int p = 0; p < 4; p++){
      sk[p] = rk[p] * 10.f;
      mk = fmaxf(mk, sk[p]);
      se[p] = re[p];
      me = fmaxf(me, se[p]);
    }
    float ssk = 0.f, sse = 0.f;
    for (int p = 0; p < 4; p++){ sk[p] = expf(sk[p] - mk); ssk += sk[p]; se[p] = expf(se[p] - me); sse += se[p]; }
    float loss = 0.f;
    for (int p = 0; p < 4; p++){
      float x = sk[p] / ssk + 1e-6f, y = se[p] / sse + 1e-6f;
      loss += x * logf(x / y);
    }
    atomicAdd(acc, loss);
  }
}

__global__ void finalize_kernel(const float* __restrict__ acc, float* __restrict__ out){
  if (threadIdx.x == 0) out[13056] = acc[0] * (100000.f / 32.f);
}

// ---------------------------------------------------------------------------
extern "C" void kernel_launch(void* const* d_in, const int* in_sizes, int n_in,
                              void* d_out, int out_size, void* d_ws, size_t ws_size,
                              hipStream_t stream)
{
  (void)in_sizes; (void)n_in; (void)out_size; (void)ws_size;
  const int*   src  = (const int*)  d_in[0];
  const float* user_info = (const float*)d_in[1];
  const float* ls   = (const float*)d_in[2];
  const float* emb  = (const float*)d_in[3];
  const float* cw1  = (const float*)d_in[4];  const float* cb1 = (const float*)d_in[5];
  const float* cw2  = (const float*)d_in[6];  const float* cb2 = (const float*)d_in[7];
  const float* cw3  = (const float*)d_in[8];  const float* cb3 = (const float*)d_in[9];
  const float* tfw  = (const float*)d_in[10]; const float* tfb = (const float*)d_in[11];
  const float* wq   = (const float*)d_in[12]; const float* bq  = (const float*)d_in[13];
  const float* wk   = (const float*)d_in[14]; const float* bk  = (const float*)d_in[15];
  const float* wv   = (const float*)d_in[16]; const float* bv  = (const float*)d_in[17];
  const float* wo   = (const float*)d_in[18]; const float* bo  = (const float*)d_in[19];
  const float* l1g  = (const float*)d_in[20]; const float* l1b = (const float*)d_in[21];
  const float* fw1  = (const float*)d_in[22]; const float* fb1 = (const float*)d_in[23];
  const float* fw2  = (const float*)d_in[24]; const float* fb2 = (const float*)d_in[25];
  const float* l2g  = (const float*)d_in[26]; const float* l2b = (const float*)d_in[27];
  const float* fc1w = (const float*)d_in[28]; const float* fc1b= (const float*)d_in[29];
  const float* fc2w = (const float*)d_in[30]; const float* fc2b= (const float*)d_in[31];
  const float* fc3w = (const float*)d_in[32]; const float* fc3b= (const float*)d_in[33];
  const float* fc4w = (const float*)d_in[34]; const float* fc4b= (const float*)d_in[35];
  const float* pscale = (const float*)d_in[36];
  const float* pbias  = (const float*)d_in[37];
  float* out = (float*)d_out;
  float* ws = (float*)d_ws;

  size_t off = 0;
  auto alloc = [&](size_t n){ float* p = ws + off; off += ((n + 3) & ~(size_t)3); return p; };
  float* base = alloc(6400ULL * EMB);          // textcnn output / branch-2 x (in place)
  float* x1   = alloc((size_t)NB * 101 * EMB); // branch-1 x
  float* qb   = alloc(6400ULL * EMB);
  float* kb   = alloc(6400ULL * EMB);
  float* vb   = alloc(6400ULL * EMB);
  float* ctx  = alloc(6400ULL * EMB);          // also reused as gelu/ln_free activation
  float* proj = alloc(6400ULL * EMB);
  float* hb   = alloc(6400ULL * FFND);
  float* p2   = alloc(6400ULL * NCLS);         // fc2 output (p / p1)
  float* clsE = alloc((size_t)NB * NCLS);
  float* tok  = alloc(3200ULL * NCLS);
  float* Pb   = alloc(3200ULL * NCLS);
  float* cls3 = alloc((size_t)NB * NCLS);
  float* SLh  = alloc((size_t)NB * NCLS * NCLS);
  float* o3   = alloc((size_t)NB * NCLS);
  float* u4   = alloc((size_t)NB * NCLS);
  float* imn  = alloc((size_t)NB * NCLS);
  float* sn   = alloc((size_t)NB * NCLS);
  float* mp   = alloc(64ULL * NCLS);
  float* ma   = alloc(64ULL * EMB);
  float* cbf  = alloc(64ULL * NCLS);
  float* abf  = alloc(64ULL * EMB);
  float* lacc = alloc(4);
  unsigned short* Wb = (unsigned short*)alloc((size_t)VC * KD / 2);  // bf16 conv weights
  float* tfwT = alloc(300ULL * EMB);
  // total ~156 MB of f32 workspace

  auto gemm = [&](const float* A, const float* W, const float* bi, float* C,
                  int M, int N, int K, int act){
    dim3 g((N + 63) / 64, (M + 63) / 64);
    gemm_kernel<<<g, 256, 0, stream>>>(A, W, bi, C, M, N, K, act);
  };

  // Stage 0: weight prep (bf16 pack + transpose), graph-safe (same work every call)
  prep_w_kernel<<<(VC * KD / 4 + 255) / 256, 256, 0, stream>>>(cw1, cw2, cw3, Wb);
  prep_tfwT_kernel<<<(300 * EMB + 255) / 256, 256, 0, stream>>>(tfw, tfwT);

  // Stage 1: textcnn for all 6400 rows (+ per-row ln_free), MFMA path
  textcnn_mfma_kernel<<<6400, 256, 0, stream>>>(src, emb, Wb, tfwT, cb1, cb2, cb3, tfb, base);
  buildx1_kernel<<<(NB * 101 * EMB + 255) / 256, 256, 0, stream>>>(base, x1);

  auto encoder = [&](float* x, int S){
    int M = NB * S;
    for (int l = 0; l < NLAYERS; l++){
      gemm(x, wq + (size_t)l * EMB * EMB, bq + l * EMB, qb, M, EMB, EMB, 0);
      gemm(x, wk + (size_t)l * EMB * EMB, bk + l * EMB, kb, M, EMB, EMB, 0);
      gemm(x, wv + (size_t)l * EMB * EMB, bv + l * EMB, vb, M, EMB, EMB, 0);
      attn_kernel<<<NB * HEADS * S, 64, 0, stream>>>(qb, kb, vb, ctx, S);
      gemm(ctx, wo + (size_t)l * EMB * EMB, bo + l * EMB, proj, M, EMB, EMB, 0);
      ln_kernel<<<M, 256, 0, stream>>>(proj, x, l1g + l * EMB, l1b + l * EMB, nullptr, nullptr, x, S, 1e-5f);
      gemm(x, fw1 + (size_t)l * FFND * EMB, fb1 + l * FFND, hb, M, FFND, EMB, 1);
      gemm(hb, fw2 + (size_t)l * EMB * FFND, fb2 + l * EMB, proj, M, EMB, FFND, 0);
      ln_kernel<<<M, 256, 0, stream>>>(proj, x, l2g + l * EMB, l2b + l * EMB, nullptr, nullptr, x, S, 1e-5f);
    }
    gemm(x, fc1w, fc1b, ctx, M, EMB, EMB, 2);                                   // gelu
    ln_kernel<<<M, 256, 0, stream>>>(ctx, nullptr, nullptr, nullptr, pscale, pbias, ctx, S, 1e-12f);
    gemm(ctx, fc2w, fc2b, p2, M, NCLS, EMB, 0);
  };

  // Branch 1: S=101
  encoder(x1, 101);
  extract_kernel<<<(NB * 101 * NCLS + 255) / 256, 256, 0, stream>>>(p2, clsE, tok);
  gemm(tok, fc3w, fc3b, Pb, 3200, NCLS, NCLS, 0);
  gemm(clsE, fc3w, fc3b, cls3, NB, NCLS, NCLS, 0);
  slhat_kernel<<<NB * NCLS, 256, 0, stream>>>(Pb, ls, SLh);
  outIII_kernel<<<NB, 256, 0, stream>>>(cls3, SLh, o3);
  softmax_out_kernel<<<NB, 256, 0, stream>>>(o3, out, NCLS);                    // output 0
  softmax_out_kernel<<<NB, 256, 0, stream>>>(clsE, out + NB * NCLS, NCLS);      // output 1
  gemm(user_info, fc4w, fc4b, u4, NB, NCLS, 142, 0);
  normalize_kernel<<<64, 256, 0, stream>>>(clsE, u4, imn, sn);
  contrastive_kernel<<<1, 1024, 0, stream>>>(imn, sn, out);                     // output 3

  // Branch 2: S=200 (in place on base); ctx ends as ap_final, p2 as p1
  encoder(base, SEQ);
  zero_kernel<<<1, 64, 0, stream>>>(lacc);
  means_kernel<<<64, 256, 0, stream>>>(p2, ctx, mp, ma);
  softmax_out_kernel<<<64, 256, 0, stream>>>(mp, cbf, NCLS);
  softmax_out_kernel<<<64, 256, 0, stream>>>(ma, abf, EMB);
  klfinal_kernel<<<NB, 64, 0, stream>>>(cbf, abf, lacc);
  finalize_kernel<<<1, 64, 0, stream>>>(lacc, out);                             // output 2
}

// Round 4
// 6535.225 us; speedup vs baseline: 3.4682x; 1.8568x over previous
//
#include <hip/hip_runtime.h>
#include <math.h>

#define EMB 512
#define HEADS 8
#define NLAYERS 4
#define NB 32
#define SEQ 200
#define TOKN 50
#define DH 64
#define FFND 2048
#define NCLS 204
#define VC 640          // virtual conv channels, padded (600 real)
#define KD 1024         // conv K dim

typedef __attribute__((ext_vector_type(8))) short v8s;   // 8 bf16 in 4 VGPRs
typedef __attribute__((ext_vector_type(4))) float v4f;
typedef unsigned short ushort_t;

__device__ __forceinline__ ushort_t f2bu(float f){  // f32 -> bf16 bits, RNE
  unsigned u = __float_as_uint(f);
  return (ushort_t)((u + 0x7FFFu + ((u >> 16) & 1u)) >> 16);
}
__device__ __forceinline__ float bu2f(ushort_t u){
  return __uint_as_float(((unsigned)u) << 16);
}

// Block reduction: sum or max across the whole block.
__device__ __forceinline__ float block_reduce(float v, float* red, int nwaves, bool domax){
  int tid = threadIdx.x;
  #pragma unroll
  for (int o = 32; o > 0; o >>= 1){
    float t = __shfl_down(v, o, 64);
    v = domax ? fmaxf(v, t) : (v + t);
  }
  __syncthreads();
  if ((tid & 63) == 0) red[tid >> 6] = v;
  __syncthreads();
  float r = red[0];
  for (int i = 1; i < nwaves; i++) r = domax ? fmaxf(r, red[i]) : (r + red[i]);
  return r;
}

// ---------------------------------------------------------------------------
// Prep: pack conv weights into bf16 virtual-channel layout Wb[VC][KD].
// ---------------------------------------------------------------------------
__global__ void prep_w_kernel(const float* __restrict__ cw1, const float* __restrict__ cw2,
                              const float* __restrict__ cw3, ushort_t* __restrict__ Wb){
  int idx4 = blockIdx.x * 256 + threadIdx.x;
  if (idx4 >= VC * KD / 4) return;
  int row = idx4 >> 8;
  int k = (idx4 & 255) * 4;
  float4 v = make_float4(0.f, 0.f, 0.f, 0.f);
  const float* s = nullptr;
  if (row < 100)      s = cw1 + (size_t)row * KD;
  else if (row < 200) s = cw2 + (size_t)((row - 100) * 2 + 0) * KD;
  else if (row < 300) s = cw2 + (size_t)((row - 200) * 2 + 1) * KD;
  else if (row < 400) s = cw3 + (size_t)((row - 300) * 3 + 0) * KD;
  else if (row < 500) s = cw3 + (size_t)((row - 400) * 3 + 1) * KD;
  else if (row < 600) s = cw3 + (size_t)((row - 500) * 3 + 2) * KD;
  if (s) v = *(const float4*)(s + k);
  ushort4 o;
  o.x = f2bu(v.x); o.y = f2bu(v.y); o.z = f2bu(v.z); o.w = f2bu(v.w);
  *(ushort4*)(Wb + (size_t)row * KD + k) = o;
}

__global__ void prep_tfwT_kernel(const float* __restrict__ tfw, float* __restrict__ tfwT){
  int idx = blockIdx.x * 256 + threadIdx.x;
  if (idx >= 300 * EMB) return;
  int j = idx >> 9, o = idx & 511;
  tfwT[(size_t)j * EMB + o] = tfw[(size_t)o * 300 + j];
}

// ---------------------------------------------------------------------------
// TextCNN via MFMA: one block per sequence row (see round-3 notes).
// Sg padded to [640][54]: 27 coprime 32 -> pooling reads conflict-free.
// ---------------------------------------------------------------------------
__global__ __launch_bounds__(256, 2) void textcnn_mfma_kernel(
    const int* __restrict__ src, const float* __restrict__ emb,
    const ushort_t* __restrict__ Wb, const float* __restrict__ tfwT,
    const float* __restrict__ cb1, const float* __restrict__ cb2,
    const float* __restrict__ cb3, const float* __restrict__ tfb,
    float* __restrict__ base)
{
  __shared__ __align__(16) char smem[69120];   // max(GEMM staging 56.3KB, Sg 640*54*2)
  __shared__ float pooled[304];
  __shared__ float red[8];
  __shared__ int toks[TOKN];

  ushort_t (*Al)[40] = (ushort_t(*)[40])smem;
  ushort_t (*Wl)[40] = (ushort_t(*)[40])(smem + 5120);
  ushort_t (*Sg)[54] = (ushort_t(*)[54])smem;

  const int tid = threadIdx.x;
  const int r = blockIdx.x;
  if (tid < TOKN) toks[tid] = src[r * TOKN + tid];
  __syncthreads();

  const int lane = tid & 63;
  const int wave = tid >> 6;
  const int mh = wave >> 1;
  const int nh = wave & 1;
  const int lcol = lane & 15;
  const int lq   = lane >> 4;

  v4f acc[2][20];
  #pragma unroll
  for (int mi = 0; mi < 2; mi++)
    #pragma unroll
    for (int ni = 0; ni < 20; ni++) acc[mi][ni] = (v4f){0.f, 0.f, 0.f, 0.f};

  const int ap = tid >> 2;
  const int ak = (tid & 3) * 8;
  const float* aep = (ap < TOKN) ? (emb + (size_t)toks[ap] * KD + ak) : nullptr;

  for (int kc = 0; kc < KD / 32; kc++){
    {
      uint4 pk = make_uint4(0, 0, 0, 0);
      if (aep){
        float4 f0 = *(const float4*)(aep + kc * 32);
        float4 f1 = *(const float4*)(aep + kc * 32 + 4);
        pk.x = (unsigned)f2bu(f0.x) | ((unsigned)f2bu(f0.y) << 16);
        pk.y = (unsigned)f2bu(f0.z) | ((unsigned)f2bu(f0.w) << 16);
        pk.z = (unsigned)f2bu(f1.x) | ((unsigned)f2bu(f1.y) << 16);
        pk.w = (unsigned)f2bu(f1.z) | ((unsigned)f2bu(f1.w) << 16);
      }
      *(uint4*)&Al[ap][ak] = pk;
    }
    #pragma unroll
    for (int i = 0; i < 10; i++){
      int idx = tid + 256 * i;
      int row = idx >> 2;
      int kq = (idx & 3) * 8;
      uint4 w = *(const uint4*)(Wb + (size_t)row * KD + kc * 32 + kq);
      *(uint4*)&Wl[row][kq] = w;
    }
    __syncthreads();
    v8s af[2];
    #pragma unroll
    for (int mi = 0; mi < 2; mi++)
      af[mi] = *(const v8s*)&Al[mh * 32 + mi * 16 + lcol][lq * 8];
    #pragma unroll
    for (int ni = 0; ni < 20; ni++){
      v8s bf = *(const v8s*)&Wl[nh * 320 + ni * 16 + lcol][lq * 8];
      acc[0][ni] = __builtin_amdgcn_mfma_f32_16x16x32_bf16(af[0], bf, acc[0][ni], 0, 0, 0);
      acc[1][ni] = __builtin_amdgcn_mfma_f32_16x16x32_bf16(af[1], bf, acc[1][ni], 0, 0, 0);
    }
    __syncthreads();
  }

  #pragma unroll
  for (int mi = 0; mi < 2; mi++){
    #pragma unroll
    for (int ni = 0; ni < 20; ni++){
      int ch = nh * 320 + ni * 16 + lcol;
      #pragma unroll
      for (int rg = 0; rg < 4; rg++){
        int pos = mh * 32 + mi * 16 + lq * 4 + rg;
        if (pos < TOKN) Sg[ch][pos] = f2bu(acc[mi][ni][rg]);
      }
    }
  }
  __syncthreads();

  for (int c = tid; c < 300; c += 256){
    float mv = -1e30f;
    if (c < 100){
      float bb = cb1[c];
      for (int p = 0; p < 50; p++) mv = fmaxf(mv, bu2f(Sg[c][p]) + bb);
    } else if (c < 200){
      int o = c - 100; float bb = cb2[o];
      for (int p = 0; p < 49; p++)
        mv = fmaxf(mv, bu2f(Sg[100 + o][p]) + bu2f(Sg[200 + o][p + 1]) + bb);
    } else {
      int o = c - 200; float bb = cb3[o];
      for (int p = 0; p < 48; p++)
        mv = fmaxf(mv, bu2f(Sg[300 + o][p]) + bu2f(Sg[400 + o][p + 1]) + bu2f(Sg[500 + o][p + 2]) + bb);
    }
    pooled[c] = fmaxf(mv, 0.f);
  }
  __syncthreads();

  float v0 = tfb[tid], v1 = tfb[tid + 256];
  for (int j = 0; j < 300; j++){
    float pj = pooled[j];
    v0 = fmaf(pj, tfwT[(size_t)j * EMB + tid], v0);
    v1 = fmaf(pj, tfwT[(size_t)j * EMB + tid + 256], v1);
  }
  float tot = block_reduce(v0 + v1, red, 4, false);
  float mu = tot * (1.f / 512.f);
  float s0 = v0 - mu, s1 = v1 - mu;
  float var = block_reduce(s0 * s0 + s1 * s1, red, 4, false) * (1.f / 512.f);
  float sc = sqrtf(1.f / (var + 1e-12f));
  base[(size_t)r * EMB + tid] = s0 * sc;
  base[(size_t)r * EMB + tid + 256] = s1 * sc;
}

// ---------------------------------------------------------------------------
// Split-bf16 MFMA GEMM: C[M,N](ldc) = act(A[M,K] @ W[N,K]^T + bias[N]).
// A,W f32; on-the-fly split x = hi(trunc) + lo(RNE of remainder); 3 MFMA
// passes (hh + lh + hl) ~ f32 accuracy. 128x128 tile, 256 thr, 4 waves.
// N,K arbitrary (guards); grid x = ceil(N/128), y = ceil(M/128).
// act: 0 none, 1 relu, 2 gelu.
// ---------------------------------------------------------------------------
__global__ __launch_bounds__(256, 2) void gemm_mfma_kernel(
    const float* __restrict__ A, const float* __restrict__ W,
    const float* __restrict__ bias, float* __restrict__ C,
    int M, int N, int K, int ldc, int act)
{
  __shared__ ushort_t Ahi[128][40];
  __shared__ ushort_t Alo[128][40];
  __shared__ ushort_t Bhi[128][40];
  __shared__ ushort_t Blo[128][40];

  const int tid = threadIdx.x;
  const int m0 = blockIdx.y * 128, n0 = blockIdx.x * 128;
  const int wave = tid >> 6, lane = tid & 63;
  const int wm = (wave >> 1) * 64, wn = (wave & 1) * 64;
  const int lcol = lane & 15, lq = lane >> 4;

  v4f acc[4][4];
  #pragma unroll
  for (int i = 0; i < 4; i++)
    #pragma unroll
    for (int j = 0; j < 4; j++) acc[i][j] = (v4f){0.f, 0.f, 0.f, 0.f};

  const int srow = tid >> 1;          // 0..127
  const int skh  = (tid & 1) * 16;    // 0 / 16

  for (int k0 = 0; k0 < K; k0 += 32){
    // ---- stage A (f32 -> hi/lo bf16) ----
    {
      float av[16];
      int m = m0 + srow;
      const float* ap = A + (size_t)m * K + k0 + skh;
      bool mok = (m < M);
      if (mok && (k0 + 32 <= K)){
        #pragma unroll
        for (int q = 0; q < 4; q++){
          float4 f = ((const float4*)ap)[q];
          av[q*4+0]=f.x; av[q*4+1]=f.y; av[q*4+2]=f.z; av[q*4+3]=f.w;
        }
      } else {
        #pragma unroll
        for (int e = 0; e < 16; e++){
          int k = k0 + skh + e;
          av[e] = (mok && k < K) ? ap[e] : 0.f;
        }
      }
      uint4 uh[2], ul[2];
      #pragma unroll
      for (int h = 0; h < 2; h++){
        unsigned hw[8], lw[8];
        #pragma unroll
        for (int e = 0; e < 8; e++){
          float x = av[h*8+e];
          unsigned u = __float_as_uint(x);
          float hf = __uint_as_float(u & 0xFFFF0000u);
          hw[e] = u >> 16;
          lw[e] = f2bu(x - hf);
        }
        uh[h] = make_uint4(hw[0]|(hw[1]<<16), hw[2]|(hw[3]<<16), hw[4]|(hw[5]<<16), hw[6]|(hw[7]<<16));
        ul[h] = make_uint4(lw[0]|(lw[1]<<16), lw[2]|(lw[3]<<16), lw[4]|(lw[5]<<16), lw[6]|(lw[7]<<16));
      }
      *(uint4*)&Ahi[srow][skh]     = uh[0];
      *(uint4*)&Ahi[srow][skh + 8] = uh[1];
      *(uint4*)&Alo[srow][skh]     = ul[0];
      *(uint4*)&Alo[srow][skh + 8] = ul[1];
    }
    // ---- stage B ----
    {
      float bv[16];
      int n = n0 + srow;
      const float* bp = W + (size_t)n * K + k0 + skh;
      bool nok = (n < N);
      if (nok && (k0 + 32 <= K)){
        #pragma unroll
        for (int q = 0; q < 4; q++){
          float4 f = ((const float4*)bp)[q];
          bv[q*4+0]=f.x; bv[q*4+1]=f.y; bv[q*4+2]=f.z; bv[q*4+3]=f.w;
        }
      } else {
        #pragma unroll
        for (int e = 0; e < 16; e++){
          int k = k0 + skh + e;
          bv[e] = (nok && k < K) ? bp[e] : 0.f;
        }
      }
      uint4 uh[2], ul[2];
      #pragma unroll
      for (int h = 0; h < 2; h++){
        unsigned hw[8], lw[8];
        #pragma unroll
        for (int e = 0; e < 8; e++){
          float x = bv[h*8+e];
          unsigned u = __float_as_uint(x);
          float hf = __uint_as_float(u & 0xFFFF0000u);
          hw[e] = u >> 16;
          lw[e] = f2bu(x - hf);
        }
        uh[h] = make_uint4(hw[0]|(hw[1]<<16), hw[2]|(hw[3]<<16), hw[4]|(hw[5]<<16), hw[6]|(hw[7]<<16));
        ul[h] = make_uint4(lw[0]|(lw[1]<<16), lw[2]|(lw[3]<<16), lw[4]|(lw[5]<<16), lw[6]|(lw[7]<<16));
      }
      *(uint4*)&Bhi[srow][skh]     = uh[0];
      *(uint4*)&Bhi[srow][skh + 8] = uh[1];
      *(uint4*)&Blo[srow][skh]     = ul[0];
      *(uint4*)&Blo[srow][skh + 8] = ul[1];
    }
    __syncthreads();

    v8s ah[4], al[4];
    #pragma unroll
    for (int mi = 0; mi < 4; mi++){
      ah[mi] = *(const v8s*)&Ahi[wm + mi*16 + lcol][lq*8];
      al[mi] = *(const v8s*)&Alo[wm + mi*16 + lcol][lq*8];
    }
    #pragma unroll
    for (int ni = 0; ni < 4; ni++){
      v8s bh = *(const v8s*)&Bhi[wn + ni*16 + lcol][lq*8];
      v8s bl = *(const v8s*)&Blo[wn + ni*16 + lcol][lq*8];
      #pragma unroll
      for (int mi = 0; mi < 4; mi++){
        acc[mi][ni] = __builtin_amdgcn_mfma_f32_16x16x32_bf16(ah[mi], bh, acc[mi][ni], 0, 0, 0);
        acc[mi][ni] = __builtin_amdgcn_mfma_f32_16x16x32_bf16(al[mi], bh, acc[mi][ni], 0, 0, 0);
        acc[mi][ni] = __builtin_amdgcn_mfma_f32_16x16x32_bf16(ah[mi], bl, acc[mi][ni], 0, 0, 0);
      }
    }
    __syncthreads();
  }

  // epilogue: C layout col=lane&15, row=(lane>>4)*4+reg
  #pragma unroll
  for (int ni = 0; ni < 4; ni++){
    int n = n0 + wn + ni*16 + lcol;
    if (n >= N) continue;
    float bv = bias[n];
    #pragma unroll
    for (int mi = 0; mi < 4; mi++){
      int mbase = m0 + wm + mi*16 + lq*4;
      #pragma unroll
      for (int rg = 0; rg < 4; rg++){
        int m = mbase + rg;
        if (m >= M) continue;
        float v = acc[mi][ni][rg] + bv;
        if (act == 1) v = fmaxf(v, 0.f);
        else if (act == 2) v = 0.5f * v * (1.f + erff(v * 0.70710678118654752f));
        C[(size_t)m * ldc + n] = v;
      }
    }
  }
}

// ---------------------------------------------------------------------------
// f32 GEMM kept for tiny shapes (M=32).
// ---------------------------------------------------------------------------
__global__ __launch_bounds__(256) void gemm_kernel(
    const float* __restrict__ A, const float* __restrict__ W,
    const float* __restrict__ bias, float* __restrict__ C,
    int M, int N, int K, int act)
{
  __shared__ float As[16][64];
  __shared__ float Ws[16][64];
  const int tid = threadIdx.x;
  const int m0 = blockIdx.y * 64, n0 = blockIdx.x * 64;
  const int lr = tid >> 2;
  const int lk = (tid & 3) * 4;
  const int tx = tid & 15, ty = tid >> 4;
  float cc[4][4];
  #pragma unroll
  for (int i = 0; i < 4; i++)
    #pragma unroll
    for (int j = 0; j < 4; j++) cc[i][j] = 0.f;

  for (int k0 = 0; k0 < K; k0 += 16){
    #pragma unroll
    for (int i = 0; i < 4; i++){
      int k = k0 + lk + i;
      int m = m0 + lr;
      As[lk + i][lr] = (m < M && k < K) ? A[(size_t)m * K + k] : 0.f;
      int n = n0 + lr;
      Ws[lk + i][lr] = (n < N && k < K) ? W[(size_t)n * K + k] : 0.f;
    }
    __syncthreads();
    #pragma unroll
    for (int kk = 0; kk < 16; kk++){
      float4 a = *(const float4*)&As[kk][ty * 4];
      float4 b = *(const float4*)&Ws[kk][tx * 4];
      float av[4] = {a.x, a.y, a.z, a.w};
      float bv[4] = {b.x, b.y, b.z, b.w};
      #pragma unroll
      for (int i = 0; i < 4; i++)
        #pragma unroll
        for (int j = 0; j < 4; j++) cc[i][j] = fmaf(av[i], bv[j], cc[i][j]);
    }
    __syncthreads();
  }

  #pragma unroll
  for (int i = 0; i < 4; i++){
    int m = m0 + ty * 4 + i;
    if (m >= M) continue;
    #pragma unroll
    for (int j = 0; j < 4; j++){
      int n = n0 + tx * 4 + j;
      if (n >= N) continue;
      float v = cc[i][j] + bias[n];
      if (act == 1) v = fmaxf(v, 0.f);
      else if (act == 2) v = 0.5f * v * (1.f + erff(v * 0.70710678118654752f));
      C[(size_t)m * N + n] = v;
    }
  }
}

// ---------------------------------------------------------------------------
// LayerNorm over EMB=512 (as before).
// ---------------------------------------------------------------------------
__global__ __launch_bounds__(256) void ln_kernel(
    const float* __restrict__ X, const float* __restrict__ Res,
    const float* __restrict__ g, const float* __restrict__ bta,
    const float* __restrict__ pscale, const float* __restrict__ pbias,
    float* __restrict__ Y, int S, float eps)
{
  __shared__ float red[8];
  const int r = blockIdx.x, tid = threadIdx.x;
  size_t o0 = (size_t)r * EMB + tid;
  size_t o1 = o0 + 256;
  float v0 = X[o0] + (Res ? Res[o0] : 0.f);
  float v1 = X[o1] + (Res ? Res[o1] : 0.f);
  float tot = block_reduce(v0 + v1, red, 4, false);
  float mu = tot * (1.f / 512.f);
  float s0 = v0 - mu, s1 = v1 - mu;
  float var = block_reduce(s0 * s0 + s1 * s1, red, 4, false) * (1.f / 512.f);
  float rs = 1.f / sqrtf(var + eps);
  float y0 = s0 * rs, y1 = s1 * rs;
  if (g){
    y0 = y0 * g[tid] + bta[tid];
    y1 = y1 * g[tid + 256] + bta[tid + 256];
  }
  if (pscale){
    int b = r / S, t = r % S;
    size_t po = ((size_t)(b * 300 + t)) * EMB;
    y0 = y0 * pscale[po + tid] + pbias[po + tid];
    y1 = y1 * pscale[po + tid + 256] + pbias[po + tid + 256];
  }
  Y[o0] = y0;
  Y[o1] = y1;
}

// ---------------------------------------------------------------------------
// V column-mean per (b,h): vm[b*8+h][d] = mean_j V[b,j,h,d] (for the
// fully-masked -> exactly-uniform-softmax rows).
// ---------------------------------------------------------------------------
__global__ __launch_bounds__(64) void vmean_kernel(const float* __restrict__ qkv,
                                                   float* __restrict__ vm, int S){
  int bh = blockIdx.x; int b = bh >> 3, h = bh & 7; int d = threadIdx.x;
  const float* vr = qkv + (size_t)(b * S) * 1536 + 1024 + h * DH + d;
  float s = 0.f;
  for (int j = 0; j < S; j++) s += vr[(size_t)j * 1536];
  vm[bh * DH + d] = s / (float)S;
}

// ---------------------------------------------------------------------------
// Masked attention, mask-structure-aware. qkv = [M][1536] (Q|K|V).
//  - rowall (i==0 or (b==0,h>=6)): full unmasked softmax over S.
//  - h<6, i>0: only window [max(0,i-5), min(S-1,i+4)] (<=10 cols) survives.
//  - h>=6, b>0, i>0: ALL masked -> softmax exactly uniform -> ctx=vmean.
// ---------------------------------------------------------------------------
__global__ __launch_bounds__(64) void attn_kernel(
    const float* __restrict__ qkv, const float* __restrict__ vm,
    float* __restrict__ Ctx, int S)
{
  __shared__ float qv[DH];
  __shared__ float sc[SEQ];
  __shared__ float wts[16];
  const int tid = threadIdx.x;
  const int blk = blockIdx.x;
  const int i = blk % S;
  const int bh = blk / S;
  const int h = bh % HEADS;
  const int b = bh / HEADS;
  const size_t rowoff = ((size_t)(b * S + i)) * 1536 + h * DH;
  const size_t coff = ((size_t)(b * S + i)) * EMB + h * DH;
  const bool rowall = (i == 0) || (b == 0 && h >= 6);

  if (rowall){
    qv[tid] = qkv[rowoff + tid];
    __syncthreads();
    for (int j = tid; j < S; j += 64){
      const float* kr = qkv + ((size_t)(b * S + j)) * 1536 + 512 + h * DH;
      float d = 0.f;
      #pragma unroll
      for (int d4 = 0; d4 < 16; d4++){
        float4 kk = *(const float4*)(kr + d4 * 4);
        d = fmaf(qv[d4*4+0], kk.x, d);
        d = fmaf(qv[d4*4+1], kk.y, d);
        d = fmaf(qv[d4*4+2], kk.z, d);
        d = fmaf(qv[d4*4+3], kk.w, d);
      }
      sc[j] = d * 0.125f;
    }
    __syncthreads();
    float mx = -INFINITY;
    for (int j = tid; j < S; j += 64) mx = fmaxf(mx, sc[j]);
    #pragma unroll
    for (int o = 32; o > 0; o >>= 1) mx = fmaxf(mx, __shfl_down(mx, o, 64));
    mx = __shfl(mx, 0, 64);
    float sm = 0.f;
    for (int j = tid; j < S; j += 64){ float e = expf(sc[j] - mx); sc[j] = e; sm += e; }
    #pragma unroll
    for (int o = 32; o > 0; o >>= 1) sm += __shfl_down(sm, o, 64);
    sm = __shfl(sm, 0, 64);
    float inv = 1.f / sm;
    __syncthreads();
    float a_ = 0.f;
    const float* vr = qkv + ((size_t)(b * S)) * 1536 + 1024 + h * DH + tid;
    for (int j = 0; j < S; j++) a_ = fmaf(sc[j], vr[(size_t)j * 1536], a_);
    Ctx[coff + tid] = a_ * inv;
  } else if (h < 6){
    qv[tid] = qkv[rowoff + tid];
    __syncthreads();
    const int lo = max(0, i - 5), hi = min(S - 1, i + 4);
    const int cnt = hi - lo + 1;               // 6..10
    float s = -INFINITY;
    if (tid < cnt){
      const float* kr = qkv + ((size_t)(b * S + lo + tid)) * 1536 + 512 + h * DH;
      float d = 0.f;
      #pragma unroll
      for (int d4 = 0; d4 < 16; d4++){
        float4 kk = *(const float4*)(kr + d4 * 4);
        d = fmaf(qv[d4*4+0], kk.x, d);
        d = fmaf(qv[d4*4+1], kk.y, d);
        d = fmaf(qv[d4*4+2], kk.z, d);
        d = fmaf(qv[d4*4+3], kk.w, d);
      }
      s = d * 0.125f;
    }
    // max + sum over lanes 0..15 (width-16 butterflies)
    float mx = s;
    #pragma unroll
    for (int o = 8; o > 0; o >>= 1) mx = fmaxf(mx, __shfl_xor(mx, o, 16));
    float e = (tid < cnt) ? expf(s - mx) : 0.f;
    float sm = e;
    #pragma unroll
    for (int o = 8; o > 0; o >>= 1) sm += __shfl_xor(sm, o, 16);
    if (tid < 16) wts[tid] = e / sm;
    __syncthreads();
    float a_ = 0.f;
    const float* vr = qkv + ((size_t)(b * S + lo)) * 1536 + 1024 + h * DH + tid;
    for (int j = 0; j < cnt; j++) a_ = fmaf(wts[j], vr[(size_t)j * 1536], a_);
    Ctx[coff + tid] = a_;
  } else {
    Ctx[coff + tid] = vm[(b * HEADS + h) * DH + tid];
  }
}

// --------------------------- small utility kernels -------------------------
__global__ void buildx1_kernel(const float* __restrict__ base, float* __restrict__ x1){
  int idx = blockIdx.x * 256 + threadIdx.x;
  if (idx >= NB * 101 * EMB) return;
  int e = idx & 511;
  int bt = idx >> 9;
  int t = bt % 101, b = bt / 101;
  x1[idx] = (t == 0) ? 0.f : base[((size_t)(b * SEQ + t - 1)) * EMB + e];
}

__global__ void extract_kernel(const float* __restrict__ p2, float* __restrict__ clsE, float* __restrict__ tok){
  int idx = blockIdx.x * 256 + threadIdx.x;
  if (idx >= NB * 101 * NCLS) return;
  int n = idx % NCLS;
  int bt = idx / NCLS;
  int t = bt % 101, b = bt / 101;
  float v = p2[idx];
  if (t == 0) clsE[b * NCLS + n] = v;
  else tok[((size_t)(b * 100 + t - 1)) * NCLS + n] = v;
}

__global__ void zero_kernel(float* p){ if (threadIdx.x == 0) p[0] = 0.f; }

__global__ __launch_bounds__(256) void slhat_kernel(
    const float* __restrict__ P, const float* __restrict__ ls, float* __restrict__ SLh)
{
  int bm = blockIdx.x;
  int b = bm / NCLS, m = bm % NCLS;
  int n = threadIdx.x;
  if (n >= NCLS) return;
  const float* Pb = P + (size_t)b * 100 * NCLS;
  float s = 0.f;
  for (int t = 0; t < 100; t++) s = fmaf(Pb[t * NCLS + m], Pb[t * NCLS + n], s);
  SLh[((size_t)bm) * NCLS + n] = ls[m * NCLS + n] + 0.4f * s;
}

__global__ __launch_bounds__(256) void outIII_kernel(
    const float* __restrict__ cls3, const float* __restrict__ SLh, float* __restrict__ o3)
{
  int b = blockIdx.x, n = threadIdx.x;
  if (n >= NCLS) return;
  float s = 0.f;
  for (int m = 0; m < NCLS; m++)
    s = fmaf(cls3[b * NCLS + m], SLh[((size_t)(b * NCLS + m)) * NCLS + n], s);
  o3[b * NCLS + n] = s;
}

__global__ __launch_bounds__(256) void softmax_out_kernel(const float* __restrict__ X, float* __restrict__ O, int n){
  __shared__ float red[8];
  int r = blockIdx.x, tid = threadIdx.x;
  float mx = -INFINITY;
  for (int j = tid; j < n; j += 256) mx = fmaxf(mx, X[(size_t)r * n + j]);
  mx = block_reduce(mx, red, 4, true);
  float sm = 0.f;
  for (int j = tid; j < n; j += 256) sm += expf(X[(size_t)r * n + j] - mx);
  sm = block_reduce(sm, red, 4, false);
  for (int j = tid; j < n; j += 256) O[(size_t)r * n + j] = expf(X[(size_t)r * n + j] - mx) / sm;
}

__global__ __launch_bounds__(256) void normalize_kernel(
    const float* __restrict__ clsE, const float* __restrict__ u4,
    float* __restrict__ imn, float* __restrict__ sn)
{
  __shared__ float red[8];
  int r = blockIdx.x, tid = threadIdx.x;
  const float* s = (r < NB) ? (clsE + (size_t)r * NCLS) : (u4 + (size_t)(r - NB) * NCLS);
  float* d = (r < NB) ? (imn + (size_t)r * NCLS) : (sn + (size_t)(r - NB) * NCLS);
  float v = (tid < NCLS) ? s[tid] : 0.f;
  float ss = block_reduce(v * v, red, 4, false);
  float nrm = fmaxf(sqrtf(ss), 1e-12f);
  if (tid < NCLS) d[tid] = v / nrm;
}

__global__ __launch_bounds__(1024) void contrastive_kernel(
    const float* __restrict__ imn, const float* __restrict__ sn, float* __restrict__ out)
{
  __shared__ float sc[NB][NB];
  __shared__ float red[16];
  int tid = threadIdx.x;
  int i = tid >> 5, j = tid & 31;
  float d = 0.f;
  for (int c = 0; c < NCLS; c++) d = fmaf(imn[i * NCLS + c], sn[j * NCLS + c], d);
  sc[i][j] = d;
  __syncthreads();
  float di = sc[i][i], dj = sc[j][j];
  float v = 0.f;
  if (i != j)
    v = fmaxf(0.02f + sc[i][j] - di, 0.f) + fmaxf(0.02f + sc[i][j] - dj, 0.f);
  #pragma unroll
  for (int o = 32; o > 0; o >>= 1) v += __shfl_down(v, o, 64);
  if ((tid & 63) == 0) red[tid >> 6] = v;
  __syncthreads();
  if (tid == 0){
    float s = 0.f;
    for (int w = 0; w < 16; w++) s += red[w];
    out[13057] = s * 0.01f;
  }
}

__global__ __launch_bounds__(256) void means_kernel(
    const float* __restrict__ p1, const float* __restrict__ ap,
    float* __restrict__ mp, float* __restrict__ ma)
{
  int bi = blockIdx.x;
  int b = bi >> 1, i = bi & 1;
  int start = i;
  int cnt = (i == 0) ? 100 : 199;
  float icnt = 1.f / (float)cnt;
  for (int c = threadIdx.x; c < NCLS + EMB; c += 256){
    float s = 0.f;
    if (c < NCLS){
      for (int rr = 0; rr < cnt; rr++) s += p1[((size_t)(b * SEQ + start + rr)) * NCLS + c];
      mp[(size_t)bi * NCLS + c] = s * icnt;
    } else {
      int cc = c - NCLS;
      for (int rr = 0; rr < cnt; rr++) s += ap[((size_t)(b * SEQ + start + rr)) * EMB + cc];
      ma[(size_t)bi * EMB + cc] = s * icnt;
    }
  }
}

__global__ __launch_bounds__(64) void klfinal_kernel(
    const float* __restrict__ cbuf, const float* __restrict__ abuf, float* __restrict__ acc)
{
  const int b = blockIdx.x, lane = threadIdx.x;
  float rk[4], re[4];
  #pragma unroll
  for (int pr = 0; pr < 4; pr++){
    int i = pr >> 1, j = pr & 1;
    const float* c1 = cbuf + ((size_t)(b * 2 + i)) * NCLS;
    const float* c2 = cbuf + ((size_t)(b * 2 + j)) * NCLS;
    float s = 0.f;
    for (int n = lane; n < NCLS; n += 64){
      float x = c1[n] + 1e-6f, y = c2[n] + 1e-6f;
      s += x * logf(x / y);
    }
    #pragma unroll
    for (int o = 32; o > 0; o >>= 1) s += __shfl_down(s, o, 64);
    rk[pr] = __shfl(s, 0, 64);
    const float* a1 = abuf + ((size_t)(b * 2 + i)) * EMB;
    const float* a2 = abuf + ((size_t)(b * 2 + j)) * EMB;
    float s2 = 0.f;
    for (int n = lane; n < EMB; n += 64){
      float dd = a1[n] - a2[n];
      s2 += dd * dd;
    }
    #pragma unroll
    for (int o = 32; o > 0; o >>= 1) s2 += __shfl_down(s2, o, 64);
    re[pr] = sqrtf(__shfl(s2, 0, 64) + 1e-12f);
  }
  if (lane == 0){
    float sk[4], se[4];
    float mk = -INFINITY, me = -INFINITY;
    for (int p = 0; p < 4; p++){
      sk[p] = rk[p] * 10.f;
      mk = fmaxf(mk, sk[p]);
      se[p] = re[p];
      me = fmaxf(me, se[p]);
    }
    float ssk = 0.f, sse = 0.f;
    for (int p = 0; p < 4; p++){ sk[p] = expf(sk[p] - mk); ssk += sk[p]; se[p] = expf(se[p] - me); sse += se[p]; }
    float loss = 0.f;
    for (int p = 0; p < 4; p++){
      float x = sk[p] / ssk + 1e-6f, y = se[p] / sse + 1e-6f;
      loss += x * logf(x / y);
    }
    atomicAdd(acc, loss);
  }
}

__global__ void finalize_kernel(const float* __restrict__ acc, float* __restrict__ out){
  if (threadIdx.x == 0) out[13056] = acc[0] * (100000.f / 32.f);
}

// ---------------------------------------------------------------------------
extern "C" void kernel_launch(void* const* d_in, const int* in_sizes, int n_in,
                              void* d_out, int out_size, void* d_ws, size_t ws_size,
                              hipStream_t stream)
{
  (void)in_sizes; (void)n_in; (void)out_size; (void)ws_size;
  const int*   src  = (const int*)  d_in[0];
  const float* user_info = (const float*)d_in[1];
  const float* ls   = (const float*)d_in[2];
  const float* emb  = (const float*)d_in[3];
  const float* cw1  = (const float*)d_in[4];  const float* cb1 = (const float*)d_in[5];
  const float* cw2  = (const float*)d_in[6];  const float* cb2 = (const float*)d_in[7];
  const float* cw3  = (const float*)d_in[8];  const float* cb3 = (const float*)d_in[9];
  const float* tfw  = (const float*)d_in[10]; const float* tfb = (const float*)d_in[11];
  const float* wq   = (const float*)d_in[12]; const float* bq  = (const float*)d_in[13];
  const float* wk   = (const float*)d_in[14]; const float* bk  = (const float*)d_in[15];
  const float* wv   = (const float*)d_in[16]; const float* bv  = (const float*)d_in[17];
  const float* wo   = (const float*)d_in[18]; const float* bo  = (const float*)d_in[19];
  const float* l1g  = (const float*)d_in[20]; const float* l1b = (const float*)d_in[21];
  const float* fw1  = (const float*)d_in[22]; const float* fb1 = (const float*)d_in[23];
  const float* fw2  = (const float*)d_in[24]; const float* fb2 = (const float*)d_in[25];
  const float* l2g  = (const float*)d_in[26]; const float* l2b = (const float*)d_in[27];
  const float* fc1w = (const float*)d_in[28]; const float* fc1b= (const float*)d_in[29];
  const float* fc2w = (const float*)d_in[30]; const float* fc2b= (const float*)d_in[31];
  const float* fc3w = (const float*)d_in[32]; const float* fc3b= (const float*)d_in[33];
  const float* fc4w = (const float*)d_in[34]; const float* fc4b= (const float*)d_in[35];
  const float* pscale = (const float*)d_in[36];
  const float* pbias  = (const float*)d_in[37];
  float* out = (float*)d_out;
  float* ws = (float*)d_ws;

  size_t off = 0;
  auto alloc = [&](size_t n){ float* p = ws + off; off += ((n + 3) & ~(size_t)3); return p; };
  float* base = alloc(6400ULL * EMB);
  float* x1   = alloc((size_t)NB * 101 * EMB);
  float* qkv  = alloc(6400ULL * 1536);         // Q|K|V fused rows
  float* ctx  = alloc(6400ULL * EMB);
  float* proj = alloc(6400ULL * EMB);
  float* hb   = alloc(6400ULL * FFND);
  float* p2   = alloc(6400ULL * NCLS);
  float* clsE = alloc((size_t)NB * NCLS);
  float* tok  = alloc(3200ULL * NCLS);
  float* Pb   = alloc(3200ULL * NCLS);
  float* cls3 = alloc((size_t)NB * NCLS);
  float* SLh  = alloc((size_t)NB * NCLS * NCLS);
  float* o3   = alloc((size_t)NB * NCLS);
  float* u4   = alloc((size_t)NB * NCLS);
  float* imn  = alloc((size_t)NB * NCLS);
  float* sn   = alloc((size_t)NB * NCLS);
  float* mp   = alloc(64ULL * NCLS);
  float* ma   = alloc(64ULL * EMB);
  float* cbf  = alloc(64ULL * NCLS);
  float* abf  = alloc(64ULL * EMB);
  float* lacc = alloc(4);
  float* vmb  = alloc((size_t)NB * HEADS * DH);
  ushort_t* Wb = (ushort_t*)alloc((size_t)VC * KD / 2);
  float* tfwT = alloc(300ULL * EMB);
  // ~155 MB total (same footprint as round 3)

  auto gemm_f32 = [&](const float* A, const float* W, const float* bi, float* C,
                      int M, int N, int K, int act){
    dim3 g((N + 63) / 64, (M + 63) / 64);
    gemm_kernel<<<g, 256, 0, stream>>>(A, W, bi, C, M, N, K, act);
  };
  auto gemm_mf = [&](const float* A, const float* W, const float* bi, float* C,
                     int M, int N, int K, int ldc, int act){
    dim3 g((N + 127) / 128, (M + 127) / 128);
    gemm_mfma_kernel<<<g, 256, 0, stream>>>(A, W, bi, C, M, N, K, ldc, act);
  };

  prep_w_kernel<<<(VC * KD / 4 + 255) / 256, 256, 0, stream>>>(cw1, cw2, cw3, Wb);
  prep_tfwT_kernel<<<(300 * EMB + 255) / 256, 256, 0, stream>>>(tfw, tfwT);

  textcnn_mfma_kernel<<<6400, 256, 0, stream>>>(src, emb, Wb, tfwT, cb1, cb2, cb3, tfb, base);
  buildx1_kernel<<<(NB * 101 * EMB + 255) / 256, 256, 0, stream>>>(base, x1);

  auto encoder = [&](float* x, int S){
    int M = NB * S;
    for (int l = 0; l < NLAYERS; l++){
      gemm_mf(x, wq + (size_t)l * EMB * EMB, bq + l * EMB, qkv,        M, EMB, EMB, 1536, 0);
      gemm_mf(x, wk + (size_t)l * EMB * EMB, bk + l * EMB, qkv + 512,  M, EMB, EMB, 1536, 0);
      gemm_mf(x, wv + (size_t)l * EMB * EMB, bv + l * EMB, qkv + 1024, M, EMB, EMB, 1536, 0);
      vmean_kernel<<<NB * HEADS, 64, 0, stream>>>(qkv, vmb, S);
      attn_kernel<<<NB * HEADS * S, 64, 0, stream>>>(qkv, vmb, ctx, S);
      gemm_mf(ctx, wo + (size_t)l * EMB * EMB, bo + l * EMB, proj, M, EMB, EMB, EMB, 0);
      ln_kernel<<<M, 256, 0, stream>>>(proj, x, l1g + l * EMB, l1b + l * EMB, nullptr, nullptr, x, S, 1e-5f);
      gemm_mf(x, fw1 + (size_t)l * FFND * EMB, fb1 + l * FFND, hb, M, FFND, EMB, FFND, 1);
      gemm_mf(hb, fw2 + (size_t)l * EMB * FFND, fb2 + l * EMB, proj, M, EMB, FFND, EMB, 0);
      ln_kernel<<<M, 256, 0, stream>>>(proj, x, l2g + l * EMB, l2b + l * EMB, nullptr, nullptr, x, S, 1e-5f);
    }
    gemm_mf(x, fc1w, fc1b, ctx, M, EMB, EMB, EMB, 2);                           // gelu
    ln_kernel<<<M, 256, 0, stream>>>(ctx, nullptr, nullptr, nullptr, pscale, pbias, ctx, S, 1e-12f);
    gemm_mf(ctx, fc2w, fc2b, p2, M, NCLS, EMB, NCLS, 0);
  };

  // Branch 1: S=101
  encoder(x1, 101);
  extract_kernel<<<(NB * 101 * NCLS + 255) / 256, 256, 0, stream>>>(p2, clsE, tok);
  gemm_mf(tok, fc3w, fc3b, Pb, 3200, NCLS, NCLS, NCLS, 0);
  gemm_f32(clsE, fc3w, fc3b, cls3, NB, NCLS, NCLS, 0);
  slhat_kernel<<<NB * NCLS, 256, 0, stream>>>(Pb, ls, SLh);
  outIII_kernel<<<NB, 256, 0, stream>>>(cls3, SLh, o3);
  softmax_out_kernel<<<NB, 256, 0, stream>>>(o3, out, NCLS);                    // output 0
  softmax_out_kernel<<<NB, 256, 0, stream>>>(clsE, out + NB * NCLS, NCLS);      // output 1
  gemm_f32(user_info, fc4w, fc4b, u4, NB, NCLS, 142, 0);
  normalize_kernel<<<64, 256, 0, stream>>>(clsE, u4, imn, sn);
  contrastive_kernel<<<1, 1024, 0, stream>>>(imn, sn, out);                     // output 3

  // Branch 2: S=200
  encoder(base, SEQ);
  zero_kernel<<<1, 64, 0, stream>>>(lacc);
  means_kernel<<<64, 256, 0, stream>>>(p2, ctx, mp, ma);
  softmax_out_kernel<<<64, 256, 0, stream>>>(mp, cbf, NCLS);
  softmax_out_kernel<<<64, 256, 0, stream>>>(ma, abf, EMB);
  klfinal_kernel<<<NB, 64, 0, stream>>>(cbf, abf, lacc);
  finalize_kernel<<<1, 64, 0, stream>>>(lacc, out);                             // output 2
}

// Round 5
// 6060.372 us; speedup vs baseline: 3.7399x; 1.0784x over previous
//
#include <hip/hip_runtime.h>
#include <math.h>

#define EMB 512
#define HEADS 8
#define NLAYERS 4
#define NB 32
#define SEQ 200
#define TOKN 50
#define DH 64
#define FFND 2048
#define NCLS 204
#define VC 640          // virtual conv channels, padded (600 real)
#define KD 1024         // conv K dim
#define CCH 8           // conv row-chunks
#define CROWS (6400/CCH)        // 800 seq rows per chunk
#define CM (CROWS*TOKN)         // 40000 GEMM M-rows per chunk

typedef __attribute__((ext_vector_type(8))) short v8s;
typedef __attribute__((ext_vector_type(4))) float v4f;
typedef unsigned short ushort_t;

__device__ __forceinline__ ushort_t f2bu(float f){  // f32 -> bf16 bits, RNE
  unsigned u = __float_as_uint(f);
  return (ushort_t)((u + 0x7FFFu + ((u >> 16) & 1u)) >> 16);
}
__device__ __forceinline__ float bu2f(ushort_t u){
  return __uint_as_float(((unsigned)u) << 16);
}

__device__ __forceinline__ float block_reduce(float v, float* red, int nwaves, bool domax){
  int tid = threadIdx.x;
  #pragma unroll
  for (int o = 32; o > 0; o >>= 1){
    float t = __shfl_down(v, o, 64);
    v = domax ? fmaxf(v, t) : (v + t);
  }
  __syncthreads();
  if ((tid & 63) == 0) red[tid >> 6] = v;
  __syncthreads();
  float r = red[0];
  for (int i = 1; i < nwaves; i++) r = domax ? fmaxf(r, red[i]) : (r + red[i]);
  return r;
}

// ---------------------------------------------------------------------------
// Prep kernels
// ---------------------------------------------------------------------------
__global__ void prep_w_kernel(const float* __restrict__ cw1, const float* __restrict__ cw2,
                              const float* __restrict__ cw3, ushort_t* __restrict__ Wb){
  int idx4 = blockIdx.x * 256 + threadIdx.x;
  if (idx4 >= VC * KD / 4) return;
  int row = idx4 >> 8;
  int k = (idx4 & 255) * 4;
  float4 v = make_float4(0.f, 0.f, 0.f, 0.f);
  const float* s = nullptr;
  if (row < 100)      s = cw1 + (size_t)row * KD;
  else if (row < 200) s = cw2 + (size_t)((row - 100) * 2 + 0) * KD;
  else if (row < 300) s = cw2 + (size_t)((row - 200) * 2 + 1) * KD;
  else if (row < 400) s = cw3 + (size_t)((row - 300) * 3 + 0) * KD;
  else if (row < 500) s = cw3 + (size_t)((row - 400) * 3 + 1) * KD;
  else if (row < 600) s = cw3 + (size_t)((row - 500) * 3 + 2) * KD;
  if (s) v = *(const float4*)(s + k);
  ushort4 o;
  o.x = f2bu(v.x); o.y = f2bu(v.y); o.z = f2bu(v.z); o.w = f2bu(v.w);
  *(ushort4*)(Wb + (size_t)row * KD + k) = o;
}

__global__ void prep_tfwT_kernel(const float* __restrict__ tfw, float* __restrict__ tfwT){
  int idx = blockIdx.x * 256 + threadIdx.x;
  if (idx >= 300 * EMB) return;
  int j = idx >> 9, o = idx & 511;
  tfwT[(size_t)j * EMB + o] = tfw[(size_t)o * 300 + j];
}

// split f32 -> (hi bf16 trunc, lo bf16 RNE of remainder)
__global__ void split_kernel(const float* __restrict__ src, ushort_t* __restrict__ hi,
                             ushort_t* __restrict__ lo, int n){
  int i4 = (blockIdx.x * 256 + threadIdx.x) * 4;
  if (i4 >= n) return;
  float4 f = *(const float4*)(src + i4);
  float x[4] = {f.x, f.y, f.z, f.w};
  ushort4 h, l;
  ushort_t hh[4], ll[4];
  #pragma unroll
  for (int e = 0; e < 4; e++){
    unsigned u = __float_as_uint(x[e]);
    float hf = __uint_as_float(u & 0xFFFF0000u);
    hh[e] = (ushort_t)(u >> 16);
    ll[e] = f2bu(x[e] - hf);
  }
  h.x=hh[0]; h.y=hh[1]; h.z=hh[2]; h.w=hh[3];
  l.x=ll[0]; l.y=ll[1]; l.z=ll[2]; l.w=ll[3];
  *(ushort4*)(hi + i4) = h;
  *(ushort4*)(lo + i4) = l;
}

__global__ void qkvbias_kernel(const float* __restrict__ bq, const float* __restrict__ bk,
                               const float* __restrict__ bv, float* __restrict__ bqkv){
  int l = blockIdx.x;
  for (int j = threadIdx.x; j < 1536; j += 256){
    float v;
    if (j < 512) v = bq[l * 512 + j];
    else if (j < 1024) v = bk[l * 512 + j - 512];
    else v = bv[l * 512 + j - 1024];
    bqkv[l * 1536 + j] = v;
  }
}

// ---------------------------------------------------------------------------
// Conv GEMM (textcnn stage 1): C[m][n] = E[m] . Wb[n], m = chunk GEMM row
// (seq row * 50 + pos), n = virtual channel. bf16 in/out, f32 accum.
// 128x128 tile, 4 waves, 16 MFMA per wave-chunk. tok = src offset per chunk.
// ---------------------------------------------------------------------------
__global__ __launch_bounds__(256, 4) void conv_gemm_kernel(
    const int* __restrict__ tok, const float* __restrict__ emb,
    const ushort_t* __restrict__ Wb, ushort_t* __restrict__ Cout, int Mc)
{
  __shared__ ushort_t Al[128][40];
  __shared__ ushort_t Bl[128][40];
  const int tid = threadIdx.x;
  const int n0 = blockIdx.x * 128;
  const int m0 = blockIdx.y * 128;
  const int wave = tid >> 6, lane = tid & 63;
  const int wm = (wave >> 1) * 64, wn = (wave & 1) * 64;
  const int lcol = lane & 15, lq = lane >> 4;

  v4f acc[4][4];
  #pragma unroll
  for (int i = 0; i < 4; i++)
    #pragma unroll
    for (int j = 0; j < 4; j++) acc[i][j] = (v4f){0.f, 0.f, 0.f, 0.f};

  const int srow = tid >> 1, skh = (tid & 1) * 16;
  const int am = m0 + srow;
  const float* aep = (am < Mc) ? (emb + (size_t)tok[am] * KD + skh) : nullptr;
  const ushort_t* bep = Wb + (size_t)(n0 + srow) * KD + skh;

  for (int k0 = 0; k0 < KD; k0 += 32){
    uint4 p0 = make_uint4(0,0,0,0), p1 = make_uint4(0,0,0,0);
    if (aep){
      float4 f0 = *(const float4*)(aep + k0);
      float4 f1 = *(const float4*)(aep + k0 + 4);
      float4 f2 = *(const float4*)(aep + k0 + 8);
      float4 f3 = *(const float4*)(aep + k0 + 12);
      p0.x = (unsigned)f2bu(f0.x) | ((unsigned)f2bu(f0.y) << 16);
      p0.y = (unsigned)f2bu(f0.z) | ((unsigned)f2bu(f0.w) << 16);
      p0.z = (unsigned)f2bu(f1.x) | ((unsigned)f2bu(f1.y) << 16);
      p0.w = (unsigned)f2bu(f1.z) | ((unsigned)f2bu(f1.w) << 16);
      p1.x = (unsigned)f2bu(f2.x) | ((unsigned)f2bu(f2.y) << 16);
      p1.y = (unsigned)f2bu(f2.z) | ((unsigned)f2bu(f2.w) << 16);
      p1.z = (unsigned)f2bu(f3.x) | ((unsigned)f2bu(f3.y) << 16);
      p1.w = (unsigned)f2bu(f3.z) | ((unsigned)f2bu(f3.w) << 16);
    }
    *(uint4*)&Al[srow][skh]     = p0;
    *(uint4*)&Al[srow][skh + 8] = p1;
    uint4 b0 = *(const uint4*)(bep + k0);
    uint4 b1 = *(const uint4*)(bep + k0 + 8);
    *(uint4*)&Bl[srow][skh]     = b0;
    *(uint4*)&Bl[srow][skh + 8] = b1;
    __syncthreads();

    v8s af[4];
    #pragma unroll
    for (int mi = 0; mi < 4; mi++)
      af[mi] = *(const v8s*)&Al[wm + mi*16 + lcol][lq*8];
    #pragma unroll
    for (int ni = 0; ni < 4; ni++){
      v8s bf = *(const v8s*)&Bl[wn + ni*16 + lcol][lq*8];
      #pragma unroll
      for (int mi = 0; mi < 4; mi++)
        acc[mi][ni] = __builtin_amdgcn_mfma_f32_16x16x32_bf16(af[mi], bf, acc[mi][ni], 0, 0, 0);
    }
    __syncthreads();
  }

  #pragma unroll
  for (int ni = 0; ni < 4; ni++){
    int n = n0 + wn + ni*16 + lcol;
    #pragma unroll
    for (int mi = 0; mi < 4; mi++){
      int mbase = m0 + wm + mi*16 + lq*4;
      #pragma unroll
      for (int rg = 0; rg < 4; rg++){
        int m = mbase + rg;
        if (m < Mc) Cout[(size_t)m * VC + n] = f2bu(acc[mi][ni][rg]);
      }
    }
  }
}

// ---------------------------------------------------------------------------
// Pool + FC + ln_free (textcnn stage 2): one block per seq row in chunk.
// Cc = conv out for this chunk; basep = base + chunk*CROWS*EMB.
// ---------------------------------------------------------------------------
__global__ __launch_bounds__(256, 2) void pool_fc_kernel(
    const ushort_t* __restrict__ Cc, const float* __restrict__ tfwT,
    const float* __restrict__ cb1, const float* __restrict__ cb2,
    const float* __restrict__ cb3, const float* __restrict__ tfb,
    float* __restrict__ basep)
{
  __shared__ ushort_t Sg[VC][54];
  __shared__ float pooled[304];
  __shared__ float red[8];
  const int tid = threadIdx.x;
  const int r = blockIdx.x;

  const unsigned* cr = (const unsigned*)(Cc + (size_t)r * TOKN * VC);
  for (int p = 0; p < TOKN; p++){
    for (int t = tid; t < VC/2; t += 256){
      unsigned u = cr[p * (VC/2) + t];
      Sg[2*t][p]   = (ushort_t)(u & 0xFFFFu);
      Sg[2*t+1][p] = (ushort_t)(u >> 16);
    }
  }
  __syncthreads();

  for (int c = tid; c < 300; c += 256){
    float mv = -1e30f;
    if (c < 100){
      float bb = cb1[c];
      for (int p = 0; p < 50; p++) mv = fmaxf(mv, bu2f(Sg[c][p]) + bb);
    } else if (c < 200){
      int o = c - 100; float bb = cb2[o];
      for (int p = 0; p < 49; p++)
        mv = fmaxf(mv, bu2f(Sg[100 + o][p]) + bu2f(Sg[200 + o][p + 1]) + bb);
    } else {
      int o = c - 200; float bb = cb3[o];
      for (int p = 0; p < 48; p++)
        mv = fmaxf(mv, bu2f(Sg[300 + o][p]) + bu2f(Sg[400 + o][p + 1]) + bu2f(Sg[500 + o][p + 2]) + bb);
    }
    pooled[c] = fmaxf(mv, 0.f);
  }
  __syncthreads();

  float v0 = tfb[tid], v1 = tfb[tid + 256];
  for (int j = 0; j < 300; j++){
    float pj = pooled[j];
    v0 = fmaf(pj, tfwT[(size_t)j * EMB + tid], v0);
    v1 = fmaf(pj, tfwT[(size_t)j * EMB + tid + 256], v1);
  }
  float tot = block_reduce(v0 + v1, red, 4, false);
  float mu = tot * (1.f / 512.f);
  float s0 = v0 - mu, s1 = v1 - mu;
  float var = block_reduce(s0 * s0 + s1 * s1, red, 4, false) * (1.f / 512.f);
  float sc = sqrtf(1.f / (var + 1e-12f));
  basep[(size_t)r * EMB + tid] = s0 * sc;
  basep[(size_t)r * EMB + tid + 256] = s1 * sc;
}

// ---------------------------------------------------------------------------
// Split-bf16 MFMA GEMM with PRE-SPLIT weights: C = act(A @ W^T + bias).
// A f32 (split on the fly); Whi/Wlo bf16 [N][K]. 3 MFMA passes.
// ---------------------------------------------------------------------------
__global__ __launch_bounds__(256, 3) void gemm_mfma_pre_kernel(
    const float* __restrict__ A, const ushort_t* __restrict__ Whi,
    const ushort_t* __restrict__ Wlo, const float* __restrict__ bias,
    float* __restrict__ C, int M, int N, int K, int ldc, int act)
{
  __shared__ ushort_t Ahi[128][40];
  __shared__ ushort_t Alo[128][40];
  __shared__ ushort_t Bhi[128][40];
  __shared__ ushort_t Blo[128][40];

  const int tid = threadIdx.x;
  const int m0 = blockIdx.y * 128, n0 = blockIdx.x * 128;
  const int wave = tid >> 6, lane = tid & 63;
  const int wm = (wave >> 1) * 64, wn = (wave & 1) * 64;
  const int lcol = lane & 15, lq = lane >> 4;

  v4f acc[4][4];
  #pragma unroll
  for (int i = 0; i < 4; i++)
    #pragma unroll
    for (int j = 0; j < 4; j++) acc[i][j] = (v4f){0.f, 0.f, 0.f, 0.f};

  const int srow = tid >> 1;
  const int skh  = (tid & 1) * 16;
  const int am = m0 + srow, bn = n0 + srow;
  const bool mok = (am < M), nok = (bn < N);
  const float* ap = A + (size_t)am * K + skh;
  const ushort_t* bph = Whi + (size_t)bn * K + skh;
  const ushort_t* bpl = Wlo + (size_t)bn * K + skh;

  for (int k0 = 0; k0 < K; k0 += 32){
    bool kfull = (k0 + 32 <= K);
    // ---- stage A (split on the fly) ----
    {
      float av[16];
      if (mok && kfull){
        #pragma unroll
        for (int q = 0; q < 4; q++){
          float4 f = *(const float4*)(ap + k0 + q*4);
          av[q*4+0]=f.x; av[q*4+1]=f.y; av[q*4+2]=f.z; av[q*4+3]=f.w;
        }
      } else {
        #pragma unroll
        for (int e = 0; e < 16; e++){
          int k = k0 + skh + e;
          av[e] = (mok && k < K) ? ap[k0 + e] : 0.f;
        }
      }
      uint4 uh[2], ul[2];
      #pragma unroll
      for (int h = 0; h < 2; h++){
        unsigned hw[8], lw[8];
        #pragma unroll
        for (int e = 0; e < 8; e++){
          float x = av[h*8+e];
          unsigned u = __float_as_uint(x);
          float hf = __uint_as_float(u & 0xFFFF0000u);
          hw[e] = u >> 16;
          lw[e] = f2bu(x - hf);
        }
        uh[h] = make_uint4(hw[0]|(hw[1]<<16), hw[2]|(hw[3]<<16), hw[4]|(hw[5]<<16), hw[6]|(hw[7]<<16));
        ul[h] = make_uint4(lw[0]|(lw[1]<<16), lw[2]|(lw[3]<<16), lw[4]|(lw[5]<<16), lw[6]|(lw[7]<<16));
      }
      *(uint4*)&Ahi[srow][skh]     = uh[0];
      *(uint4*)&Ahi[srow][skh + 8] = uh[1];
      *(uint4*)&Alo[srow][skh]     = ul[0];
      *(uint4*)&Alo[srow][skh + 8] = ul[1];
    }
    // ---- stage B (pre-split: plain copies) ----
    {
      uint4 h0 = make_uint4(0,0,0,0), h1 = h0, l0 = h0, l1 = h0;
      if (nok && kfull){
        h0 = *(const uint4*)(bph + k0);
        h1 = *(const uint4*)(bph + k0 + 8);
        l0 = *(const uint4*)(bpl + k0);
        l1 = *(const uint4*)(bpl + k0 + 8);
      } else if (nok){
        ushort_t he[16], le[16];
        #pragma unroll
        for (int e = 0; e < 16; e++){
          int k = k0 + skh + e;
          he[e] = (k < K) ? bph[k0 + e] : (ushort_t)0;
          le[e] = (k < K) ? bpl[k0 + e] : (ushort_t)0;
        }
        h0 = *(uint4*)&he[0]; h1 = *(uint4*)&he[8];
        l0 = *(uint4*)&le[0]; l1 = *(uint4*)&le[8];
      }
      *(uint4*)&Bhi[srow][skh]     = h0;
      *(uint4*)&Bhi[srow][skh + 8] = h1;
      *(uint4*)&Blo[srow][skh]     = l0;
      *(uint4*)&Blo[srow][skh + 8] = l1;
    }
    __syncthreads();

    v8s ah[4], al[4];
    #pragma unroll
    for (int mi = 0; mi < 4; mi++){
      ah[mi] = *(const v8s*)&Ahi[wm + mi*16 + lcol][lq*8];
      al[mi] = *(const v8s*)&Alo[wm + mi*16 + lcol][lq*8];
    }
    #pragma unroll
    for (int ni = 0; ni < 4; ni++){
      v8s bh = *(const v8s*)&Bhi[wn + ni*16 + lcol][lq*8];
      v8s bl = *(const v8s*)&Blo[wn + ni*16 + lcol][lq*8];
      #pragma unroll
      for (int mi = 0; mi < 4; mi++){
        acc[mi][ni] = __builtin_amdgcn_mfma_f32_16x16x32_bf16(ah[mi], bh, acc[mi][ni], 0, 0, 0);
        acc[mi][ni] = __builtin_amdgcn_mfma_f32_16x16x32_bf16(al[mi], bh, acc[mi][ni], 0, 0, 0);
        acc[mi][ni] = __builtin_amdgcn_mfma_f32_16x16x32_bf16(ah[mi], bl, acc[mi][ni], 0, 0, 0);
      }
    }
    __syncthreads();
  }

  #pragma unroll
  for (int ni = 0; ni < 4; ni++){
    int n = n0 + wn + ni*16 + lcol;
    if (n >= N) continue;
    float bv = bias[n];
    #pragma unroll
    for (int mi = 0; mi < 4; mi++){
      int mbase = m0 + wm + mi*16 + lq*4;
      #pragma unroll
      for (int rg = 0; rg < 4; rg++){
        int m = mbase + rg;
        if (m >= M) continue;
        float v = acc[mi][ni][rg] + bv;
        if (act == 1) v = fmaxf(v, 0.f);
        else if (act == 2) v = 0.5f * v * (1.f + erff(v * 0.70710678118654752f));
        C[(size_t)m * ldc + n] = v;
      }
    }
  }
}

// ---------------------------------------------------------------------------
// On-the-fly split GEMM (fallback when ws too small for pre-split weights).
// ---------------------------------------------------------------------------
__global__ __launch_bounds__(256, 2) void gemm_mfma_kernel(
    const float* __restrict__ A, const float* __restrict__ W,
    const float* __restrict__ bias, float* __restrict__ C,
    int M, int N, int K, int ldc, int act)
{
  __shared__ ushort_t Ahi[128][40];
  __shared__ ushort_t Alo[128][40];
  __shared__ ushort_t Bhi[128][40];
  __shared__ ushort_t Blo[128][40];

  const int tid = threadIdx.x;
  const int m0 = blockIdx.y * 128, n0 = blockIdx.x * 128;
  const int wave = tid >> 6, lane = tid & 63;
  const int wm = (wave >> 1) * 64, wn = (wave & 1) * 64;
  const int lcol = lane & 15, lq = lane >> 4;

  v4f acc[4][4];
  #pragma unroll
  for (int i = 0; i < 4; i++)
    #pragma unroll
    for (int j = 0; j < 4; j++) acc[i][j] = (v4f){0.f, 0.f, 0.f, 0.f};

  const int srow = tid >> 1;
  const int skh  = (tid & 1) * 16;

  for (int k0 = 0; k0 < K; k0 += 32){
    {
      float av[16];
      int m = m0 + srow;
      const float* ap = A + (size_t)m * K + k0 + skh;
      bool mok = (m < M);
      if (mok && (k0 + 32 <= K)){
        #pragma unroll
        for (int q = 0; q < 4; q++){
          float4 f = ((const float4*)ap)[q];
          av[q*4+0]=f.x; av[q*4+1]=f.y; av[q*4+2]=f.z; av[q*4+3]=f.w;
        }
      } else {
        #pragma unroll
        for (int e = 0; e < 16; e++){
          int k = k0 + skh + e;
          av[e] = (mok && k < K) ? ap[e] : 0.f;
        }
      }
      uint4 uh[2], ul[2];
      #pragma unroll
      for (int h = 0; h < 2; h++){
        unsigned hw[8], lw[8];
        #pragma unroll
        for (int e = 0; e < 8; e++){
          float x = av[h*8+e];
          unsigned u = __float_as_uint(x);
          float hf = __uint_as_float(u & 0xFFFF0000u);
          hw[e] = u >> 16;
          lw[e] = f2bu(x - hf);
        }
        uh[h] = make_uint4(hw[0]|(hw[1]<<16), hw[2]|(hw[3]<<16), hw[4]|(hw[5]<<16), hw[6]|(hw[7]<<16));
        ul[h] = make_uint4(lw[0]|(lw[1]<<16), lw[2]|(lw[3]<<16), lw[4]|(lw[5]<<16), lw[6]|(lw[7]<<16));
      }
      *(uint4*)&Ahi[srow][skh]     = uh[0];
      *(uint4*)&Ahi[srow][skh + 8] = uh[1];
      *(uint4*)&Alo[srow][skh]     = ul[0];
      *(uint4*)&Alo[srow][skh + 8] = ul[1];
    }
    {
      float bv[16];
      int n = n0 + srow;
      const float* bp = W + (size_t)n * K + k0 + skh;
      bool nok = (n < N);
      if (nok && (k0 + 32 <= K)){
        #pragma unroll
        for (int q = 0; q < 4; q++){
          float4 f = ((const float4*)bp)[q];
          bv[q*4+0]=f.x; bv[q*4+1]=f.y; bv[q*4+2]=f.z; bv[q*4+3]=f.w;
        }
      } else {
        #pragma unroll
        for (int e = 0; e < 16; e++){
          int k = k0 + skh + e;
          bv[e] = (nok && k < K) ? bp[e] : 0.f;
        }
      }
      uint4 uh[2], ul[2];
      #pragma unroll
      for (int h = 0; h < 2; h++){
        unsigned hw[8], lw[8];
        #pragma unroll
        for (int e = 0; e < 8; e++){
          float x = bv[h*8+e];
          unsigned u = __float_as_uint(x);
          float hf = __uint_as_float(u & 0xFFFF0000u);
          hw[e] = u >> 16;
          lw[e] = f2bu(x - hf);
        }
        uh[h] = make_uint4(hw[0]|(hw[1]<<16), hw[2]|(hw[3]<<16), hw[4]|(hw[5]<<16), hw[6]|(hw[7]<<16));
        ul[h] = make_uint4(lw[0]|(lw[1]<<16), lw[2]|(lw[3]<<16), lw[4]|(lw[5]<<16), lw[6]|(lw[7]<<16));
      }
      *(uint4*)&Bhi[srow][skh]     = uh[0];
      *(uint4*)&Bhi[srow][skh + 8] = uh[1];
      *(uint4*)&Blo[srow][skh]     = ul[0];
      *(uint4*)&Blo[srow][skh + 8] = ul[1];
    }
    __syncthreads();

    v8s ah[4], al[4];
    #pragma unroll
    for (int mi = 0; mi < 4; mi++){
      ah[mi] = *(const v8s*)&Ahi[wm + mi*16 + lcol][lq*8];
      al[mi] = *(const v8s*)&Alo[wm + mi*16 + lcol][lq*8];
    }
    #pragma unroll
    for (int ni = 0; ni < 4; ni++){
      v8s bh = *(const v8s*)&Bhi[wn + ni*16 + lcol][lq*8];
      v8s bl = *(const v8s*)&Blo[wn + ni*16 + lcol][lq*8];
      #pragma unroll
      for (int mi = 0; mi < 4; mi++){
        acc[mi][ni] = __builtin_amdgcn_mfma_f32_16x16x32_bf16(ah[mi], bh, acc[mi][ni], 0, 0, 0);
        acc[mi][ni] = __builtin_amdgcn_mfma_f32_16x16x32_bf16(al[mi], bh, acc[mi][ni], 0, 0, 0);
        acc[mi][ni] = __builtin_amdgcn_mfma_f32_16x16x32_bf16(ah[mi], bl, acc[mi][ni], 0, 0, 0);
      }
    }
    __syncthreads();
  }

  #pragma unroll
  for (int ni = 0; ni < 4; ni++){
    int n = n0 + wn + ni*16 + lcol;
    if (n >= N) continue;
    float bv = bias[n];
    #pragma unroll
    for (int mi = 0; mi < 4; mi++){
      int mbase = m0 + wm + mi*16 + lq*4;
      #pragma unroll
      for (int rg = 0; rg < 4; rg++){
        int m = mbase + rg;
        if (m >= M) continue;
        float v = acc[mi][ni][rg] + bv;
        if (act == 1) v = fmaxf(v, 0.f);
        else if (act == 2) v = 0.5f * v * (1.f + erff(v * 0.70710678118654752f));
        C[(size_t)m * ldc + n] = v;
      }
    }
  }
}

// ---------------------------------------------------------------------------
// f32 GEMM kept for tiny shapes (M=32).
// ---------------------------------------------------------------------------
__global__ __launch_bounds__(256) void gemm_kernel(
    const float* __restrict__ A, const float* __restrict__ W,
    const float* __restrict__ bias, float* __restrict__ C,
    int M, int N, int K, int act)
{
  __shared__ float As[16][64];
  __shared__ float Ws[16][64];
  const int tid = threadIdx.x;
  const int m0 = blockIdx.y * 64, n0 = blockIdx.x * 64;
  const int lr = tid >> 2;
  const int lk = (tid & 3) * 4;
  const int tx = tid & 15, ty = tid >> 4;
  float cc[4][4];
  #pragma unroll
  for (int i = 0; i < 4; i++)
    #pragma unroll
    for (int j = 0; j < 4; j++) cc[i][j] = 0.f;

  for (int k0 = 0; k0 < K; k0 += 16){
    #pragma unroll
    for (int i = 0; i < 4; i++){
      int k = k0 + lk + i;
      int m = m0 + lr;
      As[lk + i][lr] = (m < M && k < K) ? A[(size_t)m * K + k] : 0.f;
      int n = n0 + lr;
      Ws[lk + i][lr] = (n < N && k < K) ? W[(size_t)n * K + k] : 0.f;
    }
    __syncthreads();
    #pragma unroll
    for (int kk = 0; kk < 16; kk++){
      float4 a = *(const float4*)&As[kk][ty * 4];
      float4 b = *(const float4*)&Ws[kk][tx * 4];
      float av[4] = {a.x, a.y, a.z, a.w};
      float bv[4] = {b.x, b.y, b.z, b.w};
      #pragma unroll
      for (int i = 0; i < 4; i++)
        #pragma unroll
        for (int j = 0; j < 4; j++) cc[i][j] = fmaf(av[i], bv[j], cc[i][j]);
    }
    __syncthreads();
  }

  #pragma unroll
  for (int i = 0; i < 4; i++){
    int m = m0 + ty * 4 + i;
    if (m >= M) continue;
    #pragma unroll
    for (int j = 0; j < 4; j++){
      int n = n0 + tx * 4 + j;
      if (n >= N) continue;
      float v = cc[i][j] + bias[n];
      if (act == 1) v = fmaxf(v, 0.f);
      else if (act == 2) v = 0.5f * v * (1.f + erff(v * 0.70710678118654752f));
      C[(size_t)m * N + n] = v;
    }
  }
}

// ---------------------------------------------------------------------------
// LayerNorm over EMB=512.
// ---------------------------------------------------------------------------
__global__ __launch_bounds__(256) void ln_kernel(
    const float* __restrict__ X, const float* __restrict__ Res,
    const float* __restrict__ g, const float* __restrict__ bta,
    const float* __restrict__ pscale, const float* __restrict__ pbias,
    float* __restrict__ Y, int S, float eps)
{
  __shared__ float red[8];
  const int r = blockIdx.x, tid = threadIdx.x;
  size_t o0 = (size_t)r * EMB + tid;
  size_t o1 = o0 + 256;
  float v0 = X[o0] + (Res ? Res[o0] : 0.f);
  float v1 = X[o1] + (Res ? Res[o1] : 0.f);
  float tot = block_reduce(v0 + v1, red, 4, false);
  float mu = tot * (1.f / 512.f);
  float s0 = v0 - mu, s1 = v1 - mu;
  float var = block_reduce(s0 * s0 + s1 * s1, red, 4, false) * (1.f / 512.f);
  float rs = 1.f / sqrtf(var + eps);
  float y0 = s0 * rs, y1 = s1 * rs;
  if (g){
    y0 = y0 * g[tid] + bta[tid];
    y1 = y1 * g[tid + 256] + bta[tid + 256];
  }
  if (pscale){
    int b = r / S, t = r % S;
    size_t po = ((size_t)(b * 300 + t)) * EMB;
    y0 = y0 * pscale[po + tid] + pbias[po + tid];
    y1 = y1 * pscale[po + tid + 256] + pbias[po + tid + 256];
  }
  Y[o0] = y0;
  Y[o1] = y1;
}

// ---------------------------------------------------------------------------
// V column-mean per (b,h) (for fully-masked uniform-softmax rows).
// ---------------------------------------------------------------------------
__global__ __launch_bounds__(64) void vmean_kernel(const float* __restrict__ qkv,
                                                   float* __restrict__ vm, int S){
  int bh = blockIdx.x; int b = bh >> 3, h = bh & 7; int d = threadIdx.x;
  const float* vr = qkv + (size_t)(b * S) * 1536 + 1024 + h * DH + d;
  float s = 0.f;
  for (int j = 0; j < S; j++) s += vr[(size_t)j * 1536];
  vm[bh * DH + d] = s / (float)S;
}

// ---------------------------------------------------------------------------
// Masked attention, mask-structure-aware (see round-4 notes).
// ---------------------------------------------------------------------------
__global__ __launch_bounds__(64) void attn_kernel(
    const float* __restrict__ qkv, const float* __restrict__ vm,
    float* __restrict__ Ctx, int S)
{
  __shared__ float qv[DH];
  __shared__ float sc[SEQ];
  __shared__ float wts[16];
  const int tid = threadIdx.x;
  const int blk = blockIdx.x;
  const int i = blk % S;
  const int bh = blk / S;
  const int h = bh % HEADS;
  const int b = bh / HEADS;
  const size_t rowoff = ((size_t)(b * S + i)) * 1536 + h * DH;
  const size_t coff = ((size_t)(b * S + i)) * EMB + h * DH;
  const bool rowall = (i == 0) || (b == 0 && h >= 6);

  if (rowall){
    qv[tid] = qkv[rowoff + tid];
    __syncthreads();
    for (int j = tid; j < S; j += 64){
      const float* kr = qkv + ((size_t)(b * S + j)) * 1536 + 512 + h * DH;
      float d = 0.f;
      #pragma unroll
      for (int d4 = 0; d4 < 16; d4++){
        float4 kk = *(const float4*)(kr + d4 * 4);
        d = fmaf(qv[d4*4+0], kk.x, d);
        d = fmaf(qv[d4*4+1], kk.y, d);
        d = fmaf(qv[d4*4+2], kk.z, d);
        d = fmaf(qv[d4*4+3], kk.w, d);
      }
      sc[j] = d * 0.125f;
    }
    __syncthreads();
    float mx = -INFINITY;
    for (int j = tid; j < S; j += 64) mx = fmaxf(mx, sc[j]);
    #pragma unroll
    for (int o = 32; o > 0; o >>= 1) mx = fmaxf(mx, __shfl_down(mx, o, 64));
    mx = __shfl(mx, 0, 64);
    float sm = 0.f;
    for (int j = tid; j < S; j += 64){ float e = expf(sc[j] - mx); sc[j] = e; sm += e; }
    #pragma unroll
    for (int o = 32; o > 0; o >>= 1) sm += __shfl_down(sm, o, 64);
    sm = __shfl(sm, 0, 64);
    float inv = 1.f / sm;
    __syncthreads();
    float a_ = 0.f;
    const float* vr = qkv + ((size_t)(b * S)) * 1536 + 1024 + h * DH + tid;
    for (int j = 0; j < S; j++) a_ = fmaf(sc[j], vr[(size_t)j * 1536], a_);
    Ctx[coff + tid] = a_ * inv;
  } else if (h < 6){
    qv[tid] = qkv[rowoff + tid];
    __syncthreads();
    const int lo = max(0, i - 5), hi = min(S - 1, i + 4);
    const int cnt = hi - lo + 1;
    float s = -INFINITY;
    if (tid < cnt){
      const float* kr = qkv + ((size_t)(b * S + lo + tid)) * 1536 + 512 + h * DH;
      float d = 0.f;
      #pragma unroll
      for (int d4 = 0; d4 < 16; d4++){
        float4 kk = *(const float4*)(kr + d4 * 4);
        d = fmaf(qv[d4*4+0], kk.x, d);
        d = fmaf(qv[d4*4+1], kk.y, d);
        d = fmaf(qv[d4*4+2], kk.z, d);
        d = fmaf(qv[d4*4+3], kk.w, d);
      }
      s = d * 0.125f;
    }
    float mx = s;
    #pragma unroll
    for (int o = 8; o > 0; o >>= 1) mx = fmaxf(mx, __shfl_xor(mx, o, 16));
    float e = (tid < cnt) ? expf(s - mx) : 0.f;
    float sm = e;
    #pragma unroll
    for (int o = 8; o > 0; o >>= 1) sm += __shfl_xor(sm, o, 16);
    if (tid < 16) wts[tid] = e / sm;
    __syncthreads();
    float a_ = 0.f;
    const float* vr = qkv + ((size_t)(b * S + lo)) * 1536 + 1024 + h * DH + tid;
    for (int j = 0; j < cnt; j++) a_ = fmaf(wts[j], vr[(size_t)j * 1536], a_);
    Ctx[coff + tid] = a_;
  } else {
    Ctx[coff + tid] = vm[(b * HEADS + h) * DH + tid];
  }
}

// --------------------------- small utility kernels -------------------------
__global__ void buildx1_kernel(const float* __restrict__ base, float* __restrict__ x1){
  int idx = blockIdx.x * 256 + threadIdx.x;
  if (idx >= NB * 101 * EMB) return;
  int e = idx & 511;
  int bt = idx >> 9;
  int t = bt % 101, b = bt / 101;
  x1[idx] = (t == 0) ? 0.f : base[((size_t)(b * SEQ + t - 1)) * EMB + e];
}

__global__ void extract_kernel(const float* __restrict__ p2, float* __restrict__ clsE, float* __restrict__ tok){
  int idx = blockIdx.x * 256 + threadIdx.x;
  if (idx >= NB * 101 * NCLS) return;
  int n = idx % NCLS;
  int bt = idx / NCLS;
  int t = bt % 101, b = bt / 101;
  float v = p2[idx];
  if (t == 0) clsE[b * NCLS + n] = v;
  else tok[((size_t)(b * 100 + t - 1)) * NCLS + n] = v;
}

__global__ void zero_kernel(float* p){ if (threadIdx.x == 0) p[0] = 0.f; }

__global__ __launch_bounds__(256) void slhat_kernel(
    const float* __restrict__ P, const float* __restrict__ ls, float* __restrict__ SLh)
{
  int bm = blockIdx.x;
  int b = bm / NCLS, m = bm % NCLS;
  int n = threadIdx.x;
  if (n >= NCLS) return;
  const float* Pb = P + (size_t)b * 100 * NCLS;
  float s = 0.f;
  for (int t = 0; t < 100; t++) s = fmaf(Pb[t * NCLS + m], Pb[t * NCLS + n], s);
  SLh[((size_t)bm) * NCLS + n] = ls[m * NCLS + n] + 0.4f * s;
}

__global__ __launch_bounds__(256) void outIII_kernel(
    const float* __restrict__ cls3, const float* __restrict__ SLh, float* __restrict__ o3)
{
  int b = blockIdx.x, n = threadIdx.x;
  if (n >= NCLS) return;
  float s = 0.f;
  for (int m = 0; m < NCLS; m++)
    s = fmaf(cls3[b * NCLS + m], SLh[((size_t)(b * NCLS + m)) * NCLS + n], s);
  o3[b * NCLS + n] = s;
}

__global__ __launch_bounds__(256) void softmax_out_kernel(const float* __restrict__ X, float* __restrict__ O, int n){
  __shared__ float red[8];
  int r = blockIdx.x, tid = threadIdx.x;
  float mx = -INFINITY;
  for (int j = tid; j < n; j += 256) mx = fmaxf(mx, X[(size_t)r * n + j]);
  mx = block_reduce(mx, red, 4, true);
  float sm = 0.f;
  for (int j = tid; j < n; j += 256) sm += expf(X[(size_t)r * n + j] - mx);
  sm = block_reduce(sm, red, 4, false);
  for (int j = tid; j < n; j += 256) O[(size_t)r * n + j] = expf(X[(size_t)r * n + j] - mx) / sm;
}

__global__ __launch_bounds__(256) void normalize_kernel(
    const float* __restrict__ clsE, const float* __restrict__ u4,
    float* __restrict__ imn, float* __restrict__ sn)
{
  __shared__ float red[8];
  int r = blockIdx.x, tid = threadIdx.x;
  const float* s = (r < NB) ? (clsE + (size_t)r * NCLS) : (u4 + (size_t)(r - NB) * NCLS);
  float* d = (r < NB) ? (imn + (size_t)r * NCLS) : (sn + (size_t)(r - NB) * NCLS);
  float v = (tid < NCLS) ? s[tid] : 0.f;
  float ss = block_reduce(v * v, red, 4, false);
  float nrm = fmaxf(sqrtf(ss), 1e-12f);
  if (tid < NCLS) d[tid] = v / nrm;
}

__global__ __launch_bounds__(1024) void contrastive_kernel(
    const float* __restrict__ imn, const float* __restrict__ sn, float* __restrict__ out)
{
  __shared__ float sc[NB][NB];
  __shared__ float red[16];
  int tid = threadIdx.x;
  int i = tid >> 5, j = tid & 31;
  float d = 0.f;
  for (int c = 0; c < NCLS; c++) d = fmaf(imn[i * NCLS + c], sn[j * NCLS + c], d);
  sc[i][j] = d;
  __syncthreads();
  float di = sc[i][i], dj = sc[j][j];
  float v = 0.f;
  if (i != j)
    v = fmaxf(0.02f + sc[i][j] - di, 0.f) + fmaxf(0.02f + sc[i][j] - dj, 0.f);
  #pragma unroll
  for (int o = 32; o > 0; o >>= 1) v += __shfl_down(v, o, 64);
  if ((tid & 63) == 0) red[tid >> 6] = v;
  __syncthreads();
  if (tid == 0){
    float s = 0.f;
    for (int w = 0; w < 16; w++) s += red[w];
    out[13057] = s * 0.01f;
  }
}

__global__ __launch_bounds__(256) void means_kernel(
    const float* __restrict__ p1, const float* __restrict__ ap,
    float* __restrict__ mp, float* __restrict__ ma)
{
  int bi = blockIdx.x;
  int b = bi >> 1, i = bi & 1;
  int start = i;
  int cnt = (i == 0) ? 100 : 199;
  float icnt = 1.f / (float)cnt;
  for (int c = threadIdx.x; c < NCLS + EMB; c += 256){
    float s = 0.f;
    if (c < NCLS){
      for (int rr = 0; rr < cnt; rr++) s += p1[((size_t)(b * SEQ + start + rr)) * NCLS + c];
      mp[(size_t)bi * NCLS + c] = s * icnt;
    } else {
      int cc = c - NCLS;
      for (int rr = 0; rr < cnt; rr++) s += ap[((size_t)(b * SEQ + start + rr)) * EMB + cc];
      ma[(size_t)bi * EMB + cc] = s * icnt;
    }
  }
}

__global__ __launch_bounds__(64) void klfinal_kernel(
    const float* __restrict__ cbuf, const float* __restrict__ abuf, float* __restrict__ acc)
{
  const int b = blockIdx.x, lane = threadIdx.x;
  float rk[4], re[4];
  #pragma unroll
  for (int pr = 0; pr < 4; pr++){
    int i = pr >> 1, j = pr & 1;
    const float* c1 = cbuf + ((size_t)(b * 2 + i)) * NCLS;
    const float* c2 = cbuf + ((size_t)(b * 2 + j)) * NCLS;
    float s = 0.f;
    for (int n = lane; n < NCLS; n += 64){
      float x = c1[n] + 1e-6f, y = c2[n] + 1e-6f;
      s += x * logf(x / y);
    }
    #pragma unroll
    for (int o = 32; o > 0; o >>= 1) s += __shfl_down(s, o, 64);
    rk[pr] = __shfl(s, 0, 64);
    const float* a1 = abuf + ((size_t)(b * 2 + i)) * EMB;
    const float* a2 = abuf + ((size_t)(b * 2 + j)) * EMB;
    float s2 = 0.f;
    for (int n = lane; n < EMB; n += 64){
      float dd = a1[n] - a2[n];
      s2 += dd * dd;
    }
    #pragma unroll
    for (int o = 32; o > 0; o >>= 1) s2 += __shfl_down(s2, o, 64);
    re[pr] = sqrtf(__shfl(s2, 0, 64) + 1e-12f);
  }
  if (lane == 0){
    float sk[4], se[4];
    float mk = -INFINITY, me = -INFINITY;
    for (int p = 0; p < 4; p++){
      sk[p] = rk[p] * 10.f;
      mk = fmaxf(mk, sk[p]);
      se[p] = re[p];
      me = fmaxf(me, se[p]);
    }
    float ssk = 0.f, sse = 0.f;
    for (int p = 0; p < 4; p++){ sk[p] = expf(sk[p] - mk); ssk += sk[p]; se[p] = expf(se[p] - me); sse += se[p]; }
    float loss = 0.f;
    for (int p = 0; p < 4; p++){
      float x = sk[p] / ssk + 1e-6f, y = se[p] / sse + 1e-6f;
      loss += x * logf(x / y);
    }
    atomicAdd(acc, loss);
  }
}

__global__ void finalize_kernel(const float* __restrict__ acc, float* __restrict__ out){
  if (threadIdx.x == 0) out[13056] = acc[0] * (100000.f / 32.f);
}

// ---------------------------------------------------------------------------
extern "C" void kernel_launch(void* const* d_in, const int* in_sizes, int n_in,
                              void* d_out, int out_size, void* d_ws, size_t ws_size,
                              hipStream_t stream)
{
  (void)in_sizes; (void)n_in; (void)out_size;
  const int*   src  = (const int*)  d_in[0];
  const float* user_info = (const float*)d_in[1];
  const float* ls   = (const float*)d_in[2];
  const float* emb  = (const float*)d_in[3];
  const float* cw1  = (const float*)d_in[4];  const float* cb1 = (const float*)d_in[5];
  const float* cw2  = (const float*)d_in[6];  const float* cb2 = (const float*)d_in[7];
  const float* cw3  = (const float*)d_in[8];  const float* cb3 = (const float*)d_in[9];
  const float* tfw  = (const float*)d_in[10]; const float* tfb = (const float*)d_in[11];
  const float* wq   = (const float*)d_in[12]; const float* bq  = (const float*)d_in[13];
  const float* wk   = (const float*)d_in[14]; const float* bk  = (const float*)d_in[15];
  const float* wv   = (const float*)d_in[16]; const float* bv  = (const float*)d_in[17];
  const float* wo   = (const float*)d_in[18]; const float* bo  = (const float*)d_in[19];
  const float* l1g  = (const float*)d_in[20]; const float* l1b = (const float*)d_in[21];
  const float* fw1  = (const float*)d_in[22]; const float* fb1 = (const float*)d_in[23];
  const float* fw2  = (const float*)d_in[24]; const float* fb2 = (const float*)d_in[25];
  const float* l2g  = (const float*)d_in[26]; const float* l2b = (const float*)d_in[27];
  const float* fc1w = (const float*)d_in[28]; const float* fc1b= (const float*)d_in[29];
  const float* fc2w = (const float*)d_in[30]; const float* fc2b= (const float*)d_in[31];
  const float* fc3w = (const float*)d_in[32]; const float* fc3b= (const float*)d_in[33];
  const float* fc4w = (const float*)d_in[34]; const float* fc4b= (const float*)d_in[35];
  const float* pscale = (const float*)d_in[36];
  const float* pbias  = (const float*)d_in[37];
  float* out = (float*)d_out;
  float* ws = (float*)d_ws;

  size_t off = 0;
  auto alloc = [&](size_t n){ float* p = ws + off; off += ((n + 3) & ~(size_t)3); return p; };
  float* base = alloc(6400ULL * EMB);
  float* x1   = alloc((size_t)NB * 101 * EMB);
  float* qkv  = alloc(6400ULL * 1536);
  float* ctx  = alloc(6400ULL * EMB);
  float* proj = alloc(6400ULL * EMB);
  float* hb   = alloc(6400ULL * FFND);         // FFN buffer; reused as conv-chunk out
  float* p2   = alloc(6400ULL * NCLS);
  float* clsE = alloc((size_t)NB * NCLS);
  float* tok  = alloc(3200ULL * NCLS);
  float* Pb   = alloc(3200ULL * NCLS);
  float* cls3 = alloc((size_t)NB * NCLS);
  float* SLh  = alloc((size_t)NB * NCLS * NCLS);
  float* o3   = alloc((size_t)NB * NCLS);
  float* u4   = alloc((size_t)NB * NCLS);
  float* imn  = alloc((size_t)NB * NCLS);
  float* sn   = alloc((size_t)NB * NCLS);
  float* mp   = alloc(64ULL * NCLS);
  float* ma   = alloc(64ULL * EMB);
  float* cbf  = alloc(64ULL * NCLS);
  float* abf  = alloc(64ULL * EMB);
  float* lacc = alloc(4);
  float* vmb  = alloc((size_t)NB * HEADS * DH);
  ushort_t* Wb = (ushort_t*)alloc((size_t)VC * KD / 2);   // conv weights bf16
  float* tfwT = alloc(300ULL * EMB);
  float* bqkv = alloc(4ULL * 1536);
  // pre-split encoder weights (bf16 hi/lo). Element offsets within each array:
  const size_t OQKV = 0, OWO = 3145728, OF1 = 4194304, OF2 = 8388608;
  const size_t OC1 = 12582912, OC2 = 12845056, OC3 = 12949504, WTOT = 12991120;
  ushort_t* WhiA = (ushort_t*)alloc((WTOT + 1) / 2);
  ushort_t* WloA = (ushort_t*)alloc((WTOT + 1) / 2);
  const bool presplit = (off * sizeof(float) <= ws_size);   // ~205 MB needed

  auto gemm_f32 = [&](const float* A, const float* W, const float* bi, float* C,
                      int M, int N, int K, int act){
    dim3 g((N + 63) / 64, (M + 63) / 64);
    gemm_kernel<<<g, 256, 0, stream>>>(A, W, bi, C, M, N, K, act);
  };
  auto gemm_fly = [&](const float* A, const float* W, const float* bi, float* C,
                      int M, int N, int K, int ldc, int act){
    dim3 g((N + 127) / 128, (M + 127) / 128);
    gemm_mfma_kernel<<<g, 256, 0, stream>>>(A, W, bi, C, M, N, K, ldc, act);
  };
  auto gemm_pre = [&](const float* A, size_t woff, const float* bi, float* C,
                      int M, int N, int K, int ldc, int act){
    dim3 g((N + 127) / 128, (M + 127) / 128);
    gemm_mfma_pre_kernel<<<g, 256, 0, stream>>>(A, WhiA + woff, WloA + woff, bi, C, M, N, K, ldc, act);
  };
  auto split = [&](const float* srcw, size_t woff, int n){
    split_kernel<<<(n / 4 + 255) / 256, 256, 0, stream>>>(srcw, WhiA + woff, WloA + woff, n);
  };

  // Stage 0: weight prep (same work every call; graph-safe)
  prep_w_kernel<<<(VC * KD / 4 + 255) / 256, 256, 0, stream>>>(cw1, cw2, cw3, Wb);
  prep_tfwT_kernel<<<(300 * EMB + 255) / 256, 256, 0, stream>>>(tfw, tfwT);
  if (presplit){
    for (int l = 0; l < NLAYERS; l++){
      split(wq + (size_t)l * 262144, OQKV + (size_t)l * 786432,          262144);
      split(wk + (size_t)l * 262144, OQKV + (size_t)l * 786432 + 262144, 262144);
      split(wv + (size_t)l * 262144, OQKV + (size_t)l * 786432 + 524288, 262144);
      split(wo + (size_t)l * 262144, OWO + (size_t)l * 262144, 262144);
      split(fw1 + (size_t)l * 1048576, OF1 + (size_t)l * 1048576, 1048576);
      split(fw2 + (size_t)l * 1048576, OF2 + (size_t)l * 1048576, 1048576);
    }
    split(fc1w, OC1, 262144);
    split(fc2w, OC2, NCLS * EMB);
    split(fc3w, OC3, NCLS * NCLS);
    qkvbias_kernel<<<4, 256, 0, stream>>>(bq, bk, bv, bqkv);
  }

  // Stage 1: textcnn = conv GEMM (chunked, reusing hb) + pool/FC/ln
  for (int c = 0; c < CCH; c++){
    conv_gemm_kernel<<<dim3(VC / 128, (CM + 127) / 128), 256, 0, stream>>>(
        src + (size_t)c * CM, emb, Wb, (ushort_t*)hb, CM);
    pool_fc_kernel<<<CROWS, 256, 0, stream>>>(
        (ushort_t*)hb, tfwT, cb1, cb2, cb3, tfb, base + (size_t)c * CROWS * EMB);
  }
  buildx1_kernel<<<(NB * 101 * EMB + 255) / 256, 256, 0, stream>>>(base, x1);

  auto encoder = [&](float* x, int S){
    int M = NB * S;
    for (int l = 0; l < NLAYERS; l++){
      if (presplit){
        gemm_pre(x, OQKV + (size_t)l * 786432, bqkv + l * 1536, qkv, M, 1536, EMB, 1536, 0);
      } else {
        gemm_fly(x, wq + (size_t)l * EMB * EMB, bq + l * EMB, qkv,        M, EMB, EMB, 1536, 0);
        gemm_fly(x, wk + (size_t)l * EMB * EMB, bk + l * EMB, qkv + 512,  M, EMB, EMB, 1536, 0);
        gemm_fly(x, wv + (size_t)l * EMB * EMB, bv + l * EMB, qkv + 1024, M, EMB, EMB, 1536, 0);
      }
      vmean_kernel<<<NB * HEADS, 64, 0, stream>>>(qkv, vmb, S);
      attn_kernel<<<NB * HEADS * S, 64, 0, stream>>>(qkv, vmb, ctx, S);
      if (presplit) gemm_pre(ctx, OWO + (size_t)l * 262144, bo + l * EMB, proj, M, EMB, EMB, EMB, 0);
      else gemm_fly(ctx, wo + (size_t)l * EMB * EMB, bo + l * EMB, proj, M, EMB, EMB, EMB, 0);
      ln_kernel<<<M, 256, 0, stream>>>(proj, x, l1g + l * EMB, l1b + l * EMB, nullptr, nullptr, x, S, 1e-5f);
      if (presplit) gemm_pre(x, OF1 + (size_t)l * 1048576, fb1 + l * FFND, hb, M, FFND, EMB, FFND, 1);
      else gemm_fly(x, fw1 + (size_t)l * FFND * EMB, fb1 + l * FFND, hb, M, FFND, EMB, FFND, 1);
      if (presplit) gemm_pre(hb, OF2 + (size_t)l * 1048576, fb2 + l * EMB, proj, M, EMB, FFND, EMB, 0);
      else gemm_fly(hb, fw2 + (size_t)l * EMB * FFND, fb2 + l * EMB, proj, M, EMB, FFND, EMB, 0);
      ln_kernel<<<M, 256, 0, stream>>>(proj, x, l2g + l * EMB, l2b + l * EMB, nullptr, nullptr, x, S, 1e-5f);
    }
    if (presplit) gemm_pre(x, OC1, fc1b, ctx, M, EMB, EMB, EMB, 2);
    else gemm_fly(x, fc1w, fc1b, ctx, M, EMB, EMB, EMB, 2);
    ln_kernel<<<M, 256, 0, stream>>>(ctx, nullptr, nullptr, nullptr, pscale, pbias, ctx, S, 1e-12f);
    if (presplit) gemm_pre(ctx, OC2, fc2b, p2, M, NCLS, EMB, NCLS, 0);
    else gemm_fly(ctx, fc2w, fc2b, p2, M, NCLS, EMB, NCLS, 0);
  };

  // Branch 1: S=101
  encoder(x1, 101);
  extract_kernel<<<(NB * 101 * NCLS + 255) / 256, 256, 0, stream>>>(p2, clsE, tok);
  if (presplit) gemm_pre(tok, OC3, fc3b, Pb, 3200, NCLS, NCLS, NCLS, 0);
  else gemm_fly(tok, fc3w, fc3b, Pb, 3200, NCLS, NCLS, NCLS, 0);
  gemm_f32(clsE, fc3w, fc3b, cls3, NB, NCLS, NCLS, 0);
  slhat_kernel<<<NB * NCLS, 256, 0, stream>>>(Pb, ls, SLh);
  outIII_kernel<<<NB, 256, 0, stream>>>(cls3, SLh, o3);
  softmax_out_kernel<<<NB, 256, 0, stream>>>(o3, out, NCLS);                    // output 0
  softmax_out_kernel<<<NB, 256, 0, stream>>>(clsE, out + NB * NCLS, NCLS);      // output 1
  gemm_f32(user_info, fc4w, fc4b, u4, NB, NCLS, 142, 0);
  normalize_kernel<<<64, 256, 0, stream>>>(clsE, u4, imn, sn);
  contrastive_kernel<<<1, 1024, 0, stream>>>(imn, sn, out);                     // output 3

  // Branch 2: S=200
  encoder(base, SEQ);
  zero_kernel<<<1, 64, 0, stream>>>(lacc);
  means_kernel<<<64, 256, 0, stream>>>(p2, ctx, mp, ma);
  softmax_out_kernel<<<64, 256, 0, stream>>>(mp, cbf, NCLS);
  softmax_out_kernel<<<64, 256, 0, stream>>>(ma, abf, EMB);
  klfinal_kernel<<<NB, 64, 0, stream>>>(cbf, abf, lacc);
  finalize_kernel<<<1, 64, 0, stream>>>(lacc, out);                             // output 2
}